// Round 1
// baseline (1527.644 us; speedup 1.0000x reference)
//
#include <hip/hip_runtime.h>

#define N_G   15135
#define E_N   242160
#define BSZ   8
#define K_TOP 7568
#define NH    128

// ---------------- utility ----------------
__global__ void zero_kernel(int* __restrict__ p, int n) {
  int i = blockIdx.x * 1024 + threadIdx.x;
  if (i < n) p[i] = 0;
}

__global__ void count_kernel(const int* __restrict__ ei, int* __restrict__ cnt) {
  int e = blockIdx.x * 256 + threadIdx.x;
  if (e < E_N) atomicAdd(&cnt[ei[E_N + e]], 1);
}

__global__ void dinv_kernel(const int* __restrict__ cnt, float* __restrict__ dinv) {
  int i = blockIdx.x * 256 + threadIdx.x;
  if (i < N_G) dinv[i] = 1.0f / sqrtf((float)(cnt[i] + 1));  // +1 = self loop
}

// single-block scan of cnt -> rowstart (exclusive); also 1/||topk_w||
__global__ __launch_bounds__(1024) void prefix_kernel(const int* __restrict__ cnt,
                                                      int* __restrict__ rowstart,
                                                      const float* __restrict__ topk_w,
                                                      float* __restrict__ scal) {
  __shared__ int buf[1024];
  __shared__ float fbuf[512];
  __shared__ int running_s;
  int tid = threadIdx.x;
  if (tid == 0) running_s = 0;
  if (tid < 512) {
    float w = (tid < 384) ? topk_w[tid] : 0.f;
    fbuf[tid] = w * w;
  }
  __syncthreads();
  for (int s = 256; s > 0; s >>= 1) {
    if (tid < s) fbuf[tid] += fbuf[tid + s];
    __syncthreads();
  }
  if (tid == 0) scal[0] = 1.0f / sqrtf(fbuf[0]);
  for (int c0 = 0; c0 < N_G; c0 += 1024) {
    __syncthreads();
    int run = running_s;
    int i = c0 + tid;
    int v = (i < N_G) ? cnt[i] : 0;
    buf[tid] = v;
    __syncthreads();
    for (int s = 1; s < 1024; s <<= 1) {
      int t = (tid >= s) ? buf[tid - s] : 0;
      __syncthreads();
      buf[tid] += t;
      __syncthreads();
    }
    if (i < N_G) rowstart[i] = run + buf[tid] - v;
    if (tid == 1023) running_s = run + buf[1023];
  }
  __syncthreads();
  if (tid == 0) rowstart[N_G] = running_s;
}

__global__ void fill_kernel(const int* __restrict__ ei, const int* __restrict__ rowstart,
                            const float* __restrict__ dinv, int* __restrict__ fillc,
                            int2* __restrict__ csr) {
  int e = blockIdx.x * 256 + threadIdx.x;
  if (e < E_N) {
    int s = ei[e], d = ei[E_N + e];
    int pos = rowstart[d] + atomicAdd(&fillc[d], 1);
    csr[pos] = make_int2(s, __float_as_int(dinv[s]));
  }
}

// ---------------- dense matmul: out[M][128] = A[M][CIN] @ W[CIN][128] ----------------
template<int CIN>
__global__ __launch_bounds__(128) void mm_kernel(const float* __restrict__ A,
                                                 const float* __restrict__ W,
                                                 float* __restrict__ out, int M) {
  __shared__ float Ast[32][68];  // transposed A tile, pad 64->68 (16B-aligned, conflict-light)
  int tid = threadIdx.x;
  int rb0 = blockIdx.x * 64;
  int c0 = (tid & 15) * 8;
  int r0 = (tid >> 4) * 8;
  float acc[8][8];
#pragma unroll
  for (int i = 0; i < 8; i++)
#pragma unroll
    for (int j = 0; j < 8; j++) acc[i][j] = 0.f;

  for (int k0 = 0; k0 < CIN; k0 += 32) {
#pragma unroll
    for (int q0 = 0; q0 < 512; q0 += 128) {
      int q = q0 + tid;
      int kk4 = (q & 7) * 4, r = q >> 3;
      int row = rb0 + r;
      float4 v = make_float4(0.f, 0.f, 0.f, 0.f);
      if (row < M) v = *(const float4*)(A + (size_t)row * CIN + k0 + kk4);
      Ast[kk4 + 0][r] = v.x; Ast[kk4 + 1][r] = v.y;
      Ast[kk4 + 2][r] = v.z; Ast[kk4 + 3][r] = v.w;
    }
    __syncthreads();
#pragma unroll 4
    for (int kk = 0; kk < 32; ++kk) {
      float a[8], b[8];
      *(float4*)&a[0] = *(const float4*)&Ast[kk][r0];
      *(float4*)&a[4] = *(const float4*)&Ast[kk][r0 + 4];
      const float* wr = W + (k0 + kk) * NH + c0;
      *(float4*)&b[0] = *(const float4*)(wr);
      *(float4*)&b[4] = *(const float4*)(wr + 4);
#pragma unroll
      for (int i = 0; i < 8; i++)
#pragma unroll
        for (int j = 0; j < 8; j++)
          acc[i][j] = fmaf(a[i], b[j], acc[i][j]);
    }
    __syncthreads();
  }
#pragma unroll
  for (int i = 0; i < 8; i++) {
    int row = rb0 + r0 + i;
    if (row < M) {
      *(float4*)(out + (size_t)row * NH + c0)     = make_float4(acc[i][0], acc[i][1], acc[i][2], acc[i][3]);
      *(float4*)(out + (size_t)row * NH + c0 + 4) = make_float4(acc[i][4], acc[i][5], acc[i][6], acc[i][7]);
    }
  }
}

// ---------------- sparse aggregation + bias + relu ----------------
// hout[b][d][c] = relu( dinv[d]*( sum_e dinv[src]*hw[b][src][c] + dinv[d]*hw[b][d][c] ) + bias[c] )
// blockIdx.x & 7 = batch -> pins each batch to one XCD (blockIdx%8 round-robin heuristic)
__global__ __launch_bounds__(256) void agg_kernel(const float* __restrict__ hw,
                                                  const int2* __restrict__ csr,
                                                  const int* __restrict__ rowstart,
                                                  const float* __restrict__ dinv,
                                                  const float* __restrict__ bias,
                                                  float* __restrict__ hout, int chalf) {
  int b = blockIdx.x & 7;
  int chunk = blockIdx.x >> 3;
  int wave = threadIdx.x >> 6, lane = threadIdx.x & 63;
  int c = chalf * 64 + lane;
  const float* hwb = hw + (size_t)b * N_G * NH;
  float bc = bias[c];
  for (int t = 0; t < 8; ++t) {
    int d = chunk * 32 + wave * 8 + t;
    if (d >= N_G) break;
    float dv = dinv[d];
    float acc = dv * hwb[(size_t)d * NH + c];
    int e1 = rowstart[d + 1];
    for (int e = rowstart[d]; e < e1; ++e) {
      int2 p = csr[e];
      acc = fmaf(__int_as_float(p.y), hwb[(size_t)p.x * NH + c], acc);
    }
    hout[((size_t)b * N_G + d) * NH + c] = fmaxf(fmaf(dv, acc, bc), 0.f);
  }
}

// ---------------- scores + keys (no xc materialization) ----------------
__global__ __launch_bounds__(256) void score_kernel(const float* __restrict__ h1,
                                                    const float* __restrict__ h2,
                                                    const float* __restrict__ h3,
                                                    const float* __restrict__ topk_w,
                                                    const float* __restrict__ fcW,
                                                    const float* __restrict__ scal,
                                                    unsigned long long* __restrict__ keys,
                                                    float* __restrict__ score,
                                                    float* __restrict__ d2a) {
  int b = blockIdx.y;
  int n = blockIdx.x * 4 + (threadIdx.x >> 6);
  int lane = threadIdx.x & 63;
  if (n >= N_G) return;
  size_t base = ((size_t)b * N_G + n) * NH;
  float d1 = 0.f, d2 = 0.f;
#pragma unroll
  for (int hh = 0; hh < 2; ++hh) {
    int h = lane + hh * 64;
    float v1 = h1[base + h], v2 = h2[base + h], v3 = h3[base + h];
    d1 += v1 * topk_w[h * 3] + v2 * topk_w[h * 3 + 1] + v3 * topk_w[h * 3 + 2];
    d2 += v1 * fcW[h * 3]    + v2 * fcW[h * 3 + 1]    + v3 * fcW[h * 3 + 2];
  }
#pragma unroll
  for (int s = 32; s > 0; s >>= 1) {
    d1 += __shfl_down(d1, s);
    d2 += __shfl_down(d2, s);
  }
  if (lane == 0) {
    int gw = b * N_G + n;
    float sc = tanhf(d1 * scal[0]);
    score[gw] = sc;
    d2a[gw] = d2;
    unsigned int u = __float_as_uint(sc);
    unsigned int k32 = (u & 0x80000000u) ? ~u : (u | 0x80000000u);  // monotone float->u32
    keys[gw] = ((unsigned long long)k32 << 32) | (unsigned long long)(0xFFFFFFFFu - (unsigned)n);
  }
}

// ---------------- exact descending rank by counting (stable tie-break via key) ----------------
__global__ __launch_bounds__(256) void rank_kernel(const unsigned long long* __restrict__ keys,
                                                   int* __restrict__ rank) {
  __shared__ unsigned long long kbuf[946];
  int b = blockIdx.y;
  int ib = blockIdx.x >> 4;   // 0..7   (i-range of 2048)
  int js = blockIdx.x & 15;   // 0..15  (j-chunk of 946)
  const unsigned long long* kb = keys + (size_t)b * N_G;
  int j0 = js * 946;
  int jn = N_G - j0; if (jn > 946) jn = 946;
  for (int q = threadIdx.x; q < jn; q += 256) kbuf[q] = kb[j0 + q];
  __syncthreads();
  unsigned long long ki[8];
  int cnt[8];
  int i0 = ib * 2048 + threadIdx.x;
#pragma unroll
  for (int t = 0; t < 8; t++) {
    int i = i0 + t * 256;
    ki[t] = (i < N_G) ? kb[i] : ~0ull;
    cnt[t] = 0;
  }
  for (int j = 0; j < jn; ++j) {
    unsigned long long kj = kbuf[j];
#pragma unroll
    for (int t = 0; t < 8; t++) cnt[t] += (kj > ki[t]) ? 1 : 0;
  }
#pragma unroll
  for (int t = 0; t < 8; t++) {
    int i = i0 + t * 256;
    if (i < N_G && cnt[t] > 0) atomicAdd(&rank[b * N_G + i], cnt[t]);
  }
}

__global__ void scat_kernel(const int* __restrict__ rank, const float* __restrict__ score,
                            const float* __restrict__ d2a, const float* __restrict__ fcb,
                            float* __restrict__ z) {
  int b = blockIdx.y;
  int i = blockIdx.x * 256 + threadIdx.x;
  if (i < N_G) {
    int r = rank[b * N_G + i];
    if (r < K_TOP) z[b * K_TOP + r] = fmaf(score[b * N_G + i], d2a[b * N_G + i], fcb[0]);
  }
}

// ---------------- lin1: hpre[b][c] += sum_r z[b][r]*W[r][c] (r-split + atomics) ----------------
__global__ __launch_bounds__(256) void lin1_kernel(const float* __restrict__ z,
                                                   const float* __restrict__ W,
                                                   float* __restrict__ hpre) {
  __shared__ float zb[237];
  int b = blockIdx.y, rs = blockIdx.x;
  int r0 = rs * 237;
  int rn = K_TOP - r0; if (rn > 237) rn = 237;
  for (int q = threadIdx.x; q < rn; q += 256) zb[q] = z[b * K_TOP + r0 + q];
  __syncthreads();
  int c = threadIdx.x;
  float a0 = 0.f, a1 = 0.f;
  for (int r = 0; r < rn; ++r) {
    float zz = zb[r];
    const float* wr = W + (size_t)(r0 + r) * 512;
    a0 = fmaf(zz, wr[c], a0);
    a1 = fmaf(zz, wr[c + 256], a1);
  }
  atomicAdd(&hpre[b * 512 + c], a0);
  atomicAdd(&hpre[b * 512 + c + 256], a1);
}

// ---------------- lin2 + log_softmax ----------------
__global__ __launch_bounds__(128) void lin2_kernel(const float* __restrict__ hpre,
                                                   const float* __restrict__ l1b,
                                                   const float* __restrict__ W2,
                                                   const float* __restrict__ l2b,
                                                   float* __restrict__ out) {
  int b = blockIdx.x, tid = threadIdx.x;
  float a0 = 0.f, a1 = 0.f;
  for (int j = tid; j < 512; j += 128) {
    float t = fmaxf(hpre[b * 512 + j] + l1b[j], 0.f);
    a0 = fmaf(t, W2[j * 2 + 0], a0);
    a1 = fmaf(t, W2[j * 2 + 1], a1);
  }
#pragma unroll
  for (int s = 32; s > 0; s >>= 1) {
    a0 += __shfl_down(a0, s);
    a1 += __shfl_down(a1, s);
  }
  __shared__ float red[2][2];
  if ((tid & 63) == 0) { red[tid >> 6][0] = a0; red[tid >> 6][1] = a1; }
  __syncthreads();
  if (tid == 0) {
    float l0 = red[0][0] + red[1][0] + l2b[0];
    float l1 = red[0][1] + red[1][1] + l2b[1];
    float m = fmaxf(l0, l1);
    float lse = m + logf(expf(l0 - m) + expf(l1 - m));
    out[b * 2 + 0] = l0 - lse;
    out[b * 2 + 1] = l1 - lse;
  }
}

extern "C" void kernel_launch(void* const* d_in, const int* in_sizes, int n_in,
                              void* d_out, int out_size, void* d_ws, size_t ws_size,
                              hipStream_t stream) {
  const float* x   = (const float*)d_in[0];
  const int*   ei  = (const int*)d_in[2];
  const float* W1  = (const float*)d_in[3];
  const float* b1  = (const float*)d_in[4];
  const float* W2  = (const float*)d_in[5];
  const float* b2  = (const float*)d_in[6];
  const float* W3  = (const float*)d_in[7];
  const float* b3  = (const float*)d_in[8];
  const float* tkw = (const float*)d_in[9];
  const float* fcW = (const float*)d_in[10];
  const float* fcb = (const float*)d_in[11];
  const float* l1W = (const float*)d_in[12];
  const float* l1b = (const float*)d_in[13];
  const float* l2W = (const float*)d_in[14];
  const float* l2b = (const float*)d_in[15];
  float* out = (float*)d_out;

  char* ws = (char*)d_ws;
  size_t off = 0;
  auto alloc = [&](size_t bytes) {
    char* p = ws + off;
    off += (bytes + 255) & ~(size_t)255;
    return p;
  };
  // zero-init region (contiguous): cnt, fillc, rank, hpre
  int*   cnt   = (int*)alloc(15136 * 4);
  int*   fillc = (int*)alloc(15136 * 4);
  int*   rank  = (int*)alloc(121088 * 4);
  float* hpre  = (float*)alloc(4096 * 4);
  int*   rowstart = (int*)alloc(15136 * 4);
  float* dinv  = (float*)alloc(15136 * 4);
  float* scal  = (float*)alloc(64);
  float* z     = (float*)alloc((size_t)BSZ * K_TOP * 4);
  float* score = (float*)alloc(121088 * 4);
  float* d2a   = (float*)alloc(121088 * 4);
  unsigned long long* keys = (unsigned long long*)alloc(121088 * 8);
  int2*  csr   = (int2*)alloc((size_t)E_N * 8);
  float* hw = (float*)alloc((size_t)BSZ * N_G * NH * 4);
  float* h1 = (float*)alloc((size_t)BSZ * N_G * NH * 4);
  float* h2 = (float*)alloc((size_t)BSZ * N_G * NH * 4);
  float* h3 = (float*)alloc((size_t)BSZ * N_G * NH * 4);
  (void)ws_size; (void)in_sizes; (void)n_in; (void)out_size;

  int zero_n = (int)(((char*)rowstart - (char*)cnt) / 4);
  zero_kernel<<<(zero_n + 1023) / 1024, 1024, 0, stream>>>(cnt, zero_n);
  count_kernel<<<(E_N + 255) / 256, 256, 0, stream>>>(ei, cnt);
  dinv_kernel<<<(N_G + 255) / 256, 256, 0, stream>>>(cnt, dinv);
  prefix_kernel<<<1, 1024, 0, stream>>>(cnt, rowstart, tkw, scal);
  fill_kernel<<<(E_N + 255) / 256, 256, 0, stream>>>(ei, rowstart, dinv, fillc, csr);

  int M = BSZ * N_G;
  dim3 mmg((M + 63) / 64);
  int aggblocks = 8 * ((N_G + 31) / 32);

  mm_kernel<64><<<mmg, 128, 0, stream>>>(x, W1, hw, M);
  agg_kernel<<<aggblocks, 256, 0, stream>>>(hw, csr, rowstart, dinv, b1, h1, 0);
  agg_kernel<<<aggblocks, 256, 0, stream>>>(hw, csr, rowstart, dinv, b1, h1, 1);
  mm_kernel<128><<<mmg, 128, 0, stream>>>(h1, W2, hw, M);
  agg_kernel<<<aggblocks, 256, 0, stream>>>(hw, csr, rowstart, dinv, b2, h2, 0);
  agg_kernel<<<aggblocks, 256, 0, stream>>>(hw, csr, rowstart, dinv, b2, h2, 1);
  mm_kernel<128><<<mmg, 128, 0, stream>>>(h2, W3, hw, M);
  agg_kernel<<<aggblocks, 256, 0, stream>>>(hw, csr, rowstart, dinv, b3, h3, 0);
  agg_kernel<<<aggblocks, 256, 0, stream>>>(hw, csr, rowstart, dinv, b3, h3, 1);

  dim3 sg((N_G + 3) / 4, BSZ);
  score_kernel<<<sg, 256, 0, stream>>>(h1, h2, h3, tkw, fcW, scal, keys, score, d2a);
  dim3 rg(128, BSZ);
  rank_kernel<<<rg, 256, 0, stream>>>(keys, rank);
  dim3 scg((N_G + 255) / 256, BSZ);
  scat_kernel<<<scg, 256, 0, stream>>>(rank, score, d2a, fcb, z);
  dim3 l1g(32, BSZ);
  lin1_kernel<<<l1g, 256, 0, stream>>>(z, l1W, hpre);
  lin2_kernel<<<BSZ, 128, 0, stream>>>(hpre, l1b, l2W, l2b, out);
}

// Round 2
// 890.336 us; speedup vs baseline: 1.7158x; 1.7158x over previous
//
#include <hip/hip_runtime.h>

#define N_G   15135
#define E_N   242160
#define BSZ   8
#define K_TOP 7568
#define NH    128

// ---------------- utility ----------------
__global__ void zero_kernel(int* __restrict__ p, int n) {
  int i = blockIdx.x * 1024 + threadIdx.x;
  if (i < n) p[i] = 0;
}

__global__ void count_kernel(const int* __restrict__ ei, int* __restrict__ cnt) {
  int e = blockIdx.x * 256 + threadIdx.x;
  if (e < E_N) atomicAdd(&cnt[ei[E_N + e]], 1);
}

__global__ void dinv_kernel(const int* __restrict__ cnt, float* __restrict__ dinv) {
  int i = blockIdx.x * 256 + threadIdx.x;
  if (i < N_G) dinv[i] = 1.0f / sqrtf((float)(cnt[i] + 1));  // +1 = self loop
}

// single-block scan of cnt -> rowstart (exclusive); also 1/||topk_w||
__global__ __launch_bounds__(1024) void prefix_kernel(const int* __restrict__ cnt,
                                                      int* __restrict__ rowstart,
                                                      const float* __restrict__ topk_w,
                                                      float* __restrict__ scal) {
  __shared__ int buf[1024];
  __shared__ float fbuf[512];
  __shared__ int running_s;
  int tid = threadIdx.x;
  if (tid == 0) running_s = 0;
  if (tid < 512) {
    float w = (tid < 384) ? topk_w[tid] : 0.f;
    fbuf[tid] = w * w;
  }
  __syncthreads();
  for (int s = 256; s > 0; s >>= 1) {
    if (tid < s) fbuf[tid] += fbuf[tid + s];
    __syncthreads();
  }
  if (tid == 0) scal[0] = 1.0f / sqrtf(fbuf[0]);
  for (int c0 = 0; c0 < N_G; c0 += 1024) {
    __syncthreads();
    int run = running_s;
    int i = c0 + tid;
    int v = (i < N_G) ? cnt[i] : 0;
    buf[tid] = v;
    __syncthreads();
    for (int s = 1; s < 1024; s <<= 1) {
      int t = (tid >= s) ? buf[tid - s] : 0;
      __syncthreads();
      buf[tid] += t;
      __syncthreads();
    }
    if (i < N_G) rowstart[i] = run + buf[tid] - v;
    if (tid == 1023) running_s = run + buf[1023];
  }
  __syncthreads();
  if (tid == 0) rowstart[N_G] = running_s;
}

__global__ void fill_kernel(const int* __restrict__ ei, const int* __restrict__ rowstart,
                            const float* __restrict__ dinv, int* __restrict__ fillc,
                            int2* __restrict__ csr) {
  int e = blockIdx.x * 256 + threadIdx.x;
  if (e < E_N) {
    int s = ei[e], d = ei[E_N + e];
    int pos = rowstart[d] + atomicAdd(&fillc[d], 1);
    csr[pos] = make_int2(s, __float_as_int(dinv[s]));
  }
}

// ---------------- dense matmul: out[M][128] = A[M][CIN] @ W[CIN][128] ----------------
template<int CIN>
__global__ __launch_bounds__(128) void mm_kernel(const float* __restrict__ A,
                                                 const float* __restrict__ W,
                                                 float* __restrict__ out, int M) {
  __shared__ float Ast[32][68];
  int tid = threadIdx.x;
  int rb0 = blockIdx.x * 64;
  int c0 = (tid & 15) * 8;
  int r0 = (tid >> 4) * 8;
  float acc[8][8];
#pragma unroll
  for (int i = 0; i < 8; i++)
#pragma unroll
    for (int j = 0; j < 8; j++) acc[i][j] = 0.f;

  for (int k0 = 0; k0 < CIN; k0 += 32) {
#pragma unroll
    for (int q0 = 0; q0 < 512; q0 += 128) {
      int q = q0 + tid;
      int kk4 = (q & 7) * 4, r = q >> 3;
      int row = rb0 + r;
      float4 v = make_float4(0.f, 0.f, 0.f, 0.f);
      if (row < M) v = *(const float4*)(A + (size_t)row * CIN + k0 + kk4);
      Ast[kk4 + 0][r] = v.x; Ast[kk4 + 1][r] = v.y;
      Ast[kk4 + 2][r] = v.z; Ast[kk4 + 3][r] = v.w;
    }
    __syncthreads();
#pragma unroll 4
    for (int kk = 0; kk < 32; ++kk) {
      float a[8], b[8];
      *(float4*)&a[0] = *(const float4*)&Ast[kk][r0];
      *(float4*)&a[4] = *(const float4*)&Ast[kk][r0 + 4];
      const float* wr = W + (k0 + kk) * NH + c0;
      *(float4*)&b[0] = *(const float4*)(wr);
      *(float4*)&b[4] = *(const float4*)(wr + 4);
#pragma unroll
      for (int i = 0; i < 8; i++)
#pragma unroll
        for (int j = 0; j < 8; j++)
          acc[i][j] = fmaf(a[i], b[j], acc[i][j]);
    }
    __syncthreads();
  }
#pragma unroll
  for (int i = 0; i < 8; i++) {
    int row = rb0 + r0 + i;
    if (row < M) {
      *(float4*)(out + (size_t)row * NH + c0)     = make_float4(acc[i][0], acc[i][1], acc[i][2], acc[i][3]);
      *(float4*)(out + (size_t)row * NH + c0 + 4) = make_float4(acc[i][4], acc[i][5], acc[i][6], acc[i][7]);
    }
  }
}

// ---------------- sparse aggregation + bias + relu (all 128 channels) ----------------
// One wave per dest: parallel edge-list load -> shfl broadcast -> independent float2 gathers.
// blockIdx.x & 7 = batch (XCD round-robin heuristic for L2 locality).
__global__ __launch_bounds__(256) void agg_kernel(const float* __restrict__ hw,
                                                  const int2* __restrict__ csr,
                                                  const int* __restrict__ rowstart,
                                                  const float* __restrict__ dinv,
                                                  const float* __restrict__ bias,
                                                  float* __restrict__ hout) {
  int b = blockIdx.x & 7;
  int chunk = blockIdx.x >> 3;
  int wave = threadIdx.x >> 6, lane = threadIdx.x & 63;
  int d = chunk * 4 + wave;
  if (d >= N_G) return;
  const float2* hwb = (const float2*)(hw + (size_t)b * N_G * NH);
  float dv = dinv[d];
  int e0 = rowstart[d], e1 = rowstart[d + 1];
  int n = e1 - e0;
  float2 vd = hwb[(size_t)d * 64 + lane];
  float a0x = dv * vd.x, a0y = dv * vd.y;
  float a1x = 0.f, a1y = 0.f, a2x = 0.f, a2y = 0.f, a3x = 0.f, a3y = 0.f;
  for (int l0 = 0; l0 < n; l0 += 64) {
    int idx = l0 + lane;
    int2 p = make_int2(0, 0);
    if (idx < n) p = csr[e0 + idx];
    int m = n - l0; if (m > 64) m = 64;
    int l = 0;
    for (; l + 4 <= m; l += 4) {
      int   s0 = __shfl(p.x, l + 0), s1 = __shfl(p.x, l + 1);
      int   s2 = __shfl(p.x, l + 2), s3 = __shfl(p.x, l + 3);
      float w0 = __int_as_float(__shfl(p.y, l + 0));
      float w1 = __int_as_float(__shfl(p.y, l + 1));
      float w2 = __int_as_float(__shfl(p.y, l + 2));
      float w3 = __int_as_float(__shfl(p.y, l + 3));
      float2 v0 = hwb[(size_t)s0 * 64 + lane];
      float2 v1 = hwb[(size_t)s1 * 64 + lane];
      float2 v2 = hwb[(size_t)s2 * 64 + lane];
      float2 v3 = hwb[(size_t)s3 * 64 + lane];
      a0x = fmaf(w0, v0.x, a0x); a0y = fmaf(w0, v0.y, a0y);
      a1x = fmaf(w1, v1.x, a1x); a1y = fmaf(w1, v1.y, a1y);
      a2x = fmaf(w2, v2.x, a2x); a2y = fmaf(w2, v2.y, a2y);
      a3x = fmaf(w3, v3.x, a3x); a3y = fmaf(w3, v3.y, a3y);
    }
    for (; l < m; ++l) {
      int   s = __shfl(p.x, l);
      float w = __int_as_float(__shfl(p.y, l));
      float2 v = hwb[(size_t)s * 64 + lane];
      a0x = fmaf(w, v.x, a0x); a0y = fmaf(w, v.y, a0y);
    }
  }
  float sx = a0x + a1x + a2x + a3x;
  float sy = a0y + a1y + a2y + a3y;
  float2 bb = ((const float2*)bias)[lane];
  float2 r;
  r.x = fmaxf(fmaf(dv, sx, bb.x), 0.f);
  r.y = fmaxf(fmaf(dv, sy, bb.y), 0.f);
  ((float2*)hout)[((size_t)b * N_G + d) * 64 + lane] = r;
}

// ---------------- scores + keys (no xc materialization, float4 loads) ----------------
// 32-lane group per node; lane sl covers channels sl*4..sl*4+3 of all 3 layers.
__global__ __launch_bounds__(256) void score_kernel(const float* __restrict__ h1,
                                                    const float* __restrict__ h2,
                                                    const float* __restrict__ h3,
                                                    const float* __restrict__ topk_w,
                                                    const float* __restrict__ fcW,
                                                    const float* __restrict__ scal,
                                                    unsigned long long* __restrict__ keys,
                                                    float* __restrict__ score,
                                                    float* __restrict__ d2a) {
  int b = blockIdx.y;
  int n = blockIdx.x * 8 + (threadIdx.x >> 5);
  int sl = threadIdx.x & 31;
  if (n >= N_G) return;
  size_t base = ((size_t)b * N_G + n) * 32 + sl;
  float4 v1 = ((const float4*)h1)[base];
  float4 v2 = ((const float4*)h2)[base];
  float4 v3 = ((const float4*)h3)[base];
  const float4* tw4 = (const float4*)topk_w;
  const float4* fw4 = (const float4*)fcW;
  float4 t0 = tw4[sl * 3 + 0], t1 = tw4[sl * 3 + 1], t2 = tw4[sl * 3 + 2];
  float4 f0 = fw4[sl * 3 + 0], f1 = fw4[sl * 3 + 1], f2 = fw4[sl * 3 + 2];
  float d1 = v1.x * t0.x + v2.x * t0.y + v3.x * t0.z
           + v1.y * t0.w + v2.y * t1.x + v3.y * t1.y
           + v1.z * t1.z + v2.z * t1.w + v3.z * t2.x
           + v1.w * t2.y + v2.w * t2.z + v3.w * t2.w;
  float d2 = v1.x * f0.x + v2.x * f0.y + v3.x * f0.z
           + v1.y * f0.w + v2.y * f1.x + v3.y * f1.y
           + v1.z * f1.z + v2.z * f1.w + v3.z * f2.x
           + v1.w * f2.y + v2.w * f2.z + v3.w * f2.w;
#pragma unroll
  for (int s = 16; s > 0; s >>= 1) {
    d1 += __shfl_down(d1, s, 32);
    d2 += __shfl_down(d2, s, 32);
  }
  if (sl == 0) {
    int gw = b * N_G + n;
    float sc = tanhf(d1 * scal[0]);
    score[gw] = sc;
    d2a[gw] = d2;
    unsigned int u = __float_as_uint(sc);
    unsigned int k32 = (u & 0x80000000u) ? ~u : (u | 0x80000000u);  // monotone float->u32
    keys[gw] = ((unsigned long long)k32 << 32) | (unsigned long long)(0xFFFFFFFFu - (unsigned)n);
  }
}

// ---------------- exact descending rank by counting (stable tie-break via key) ----------------
__global__ __launch_bounds__(256) void rank_kernel(const unsigned long long* __restrict__ keys,
                                                   int* __restrict__ rank) {
  __shared__ unsigned long long kbuf[946];
  int b = blockIdx.y;
  int ib = blockIdx.x >> 4;   // 0..7   (i-range of 2048)
  int js = blockIdx.x & 15;   // 0..15  (j-chunk of 946)
  const unsigned long long* kb = keys + (size_t)b * N_G;
  int j0 = js * 946;
  int jn = N_G - j0; if (jn > 946) jn = 946;
  for (int q = threadIdx.x; q < jn; q += 256) kbuf[q] = kb[j0 + q];
  __syncthreads();
  unsigned long long ki[8];
  int cnt[8];
  int i0 = ib * 2048 + threadIdx.x;
#pragma unroll
  for (int t = 0; t < 8; t++) {
    int i = i0 + t * 256;
    ki[t] = (i < N_G) ? kb[i] : ~0ull;
    cnt[t] = 0;
  }
  for (int j = 0; j < jn; ++j) {
    unsigned long long kj = kbuf[j];
#pragma unroll
    for (int t = 0; t < 8; t++) cnt[t] += (kj > ki[t]) ? 1 : 0;
  }
#pragma unroll
  for (int t = 0; t < 8; t++) {
    int i = i0 + t * 256;
    if (i < N_G && cnt[t] > 0) atomicAdd(&rank[b * N_G + i], cnt[t]);
  }
}

__global__ void scat_kernel(const int* __restrict__ rank, const float* __restrict__ score,
                            const float* __restrict__ d2a, const float* __restrict__ fcb,
                            float* __restrict__ z) {
  int b = blockIdx.y;
  int i = blockIdx.x * 256 + threadIdx.x;
  if (i < N_G) {
    int r = rank[b * N_G + i];
    if (r < K_TOP) z[b * K_TOP + r] = fmaf(score[b * N_G + i], d2a[b * N_G + i], fcb[0]);
  }
}

// ---------------- lin1: hpre[b][c] += sum_r z[b][r]*W[r][c] (r-split + atomics) ----------------
__global__ __launch_bounds__(256) void lin1_kernel(const float* __restrict__ z,
                                                   const float* __restrict__ W,
                                                   float* __restrict__ hpre) {
  __shared__ float zb[237];
  int b = blockIdx.y, rs = blockIdx.x;
  int r0 = rs * 237;
  int rn = K_TOP - r0; if (rn > 237) rn = 237;
  for (int q = threadIdx.x; q < rn; q += 256) zb[q] = z[b * K_TOP + r0 + q];
  __syncthreads();
  int c = threadIdx.x;
  float a0 = 0.f, a1 = 0.f;
  for (int r = 0; r < rn; ++r) {
    float zz = zb[r];
    const float* wr = W + (size_t)(r0 + r) * 512;
    a0 = fmaf(zz, wr[c], a0);
    a1 = fmaf(zz, wr[c + 256], a1);
  }
  atomicAdd(&hpre[b * 512 + c], a0);
  atomicAdd(&hpre[b * 512 + c + 256], a1);
}

// ---------------- lin2 + log_softmax ----------------
__global__ __launch_bounds__(128) void lin2_kernel(const float* __restrict__ hpre,
                                                   const float* __restrict__ l1b,
                                                   const float* __restrict__ W2,
                                                   const float* __restrict__ l2b,
                                                   float* __restrict__ out) {
  int b = blockIdx.x, tid = threadIdx.x;
  float a0 = 0.f, a1 = 0.f;
  for (int j = tid; j < 512; j += 128) {
    float t = fmaxf(hpre[b * 512 + j] + l1b[j], 0.f);
    a0 = fmaf(t, W2[j * 2 + 0], a0);
    a1 = fmaf(t, W2[j * 2 + 1], a1);
  }
#pragma unroll
  for (int s = 32; s > 0; s >>= 1) {
    a0 += __shfl_down(a0, s);
    a1 += __shfl_down(a1, s);
  }
  __shared__ float red[2][2];
  if ((tid & 63) == 0) { red[tid >> 6][0] = a0; red[tid >> 6][1] = a1; }
  __syncthreads();
  if (tid == 0) {
    float l0 = red[0][0] + red[1][0] + l2b[0];
    float l1 = red[0][1] + red[1][1] + l2b[1];
    float m = fmaxf(l0, l1);
    float lse = m + logf(expf(l0 - m) + expf(l1 - m));
    out[b * 2 + 0] = l0 - lse;
    out[b * 2 + 1] = l1 - lse;
  }
}

extern "C" void kernel_launch(void* const* d_in, const int* in_sizes, int n_in,
                              void* d_out, int out_size, void* d_ws, size_t ws_size,
                              hipStream_t stream) {
  const float* x   = (const float*)d_in[0];
  const int*   ei  = (const int*)d_in[2];
  const float* W1  = (const float*)d_in[3];
  const float* b1  = (const float*)d_in[4];
  const float* W2  = (const float*)d_in[5];
  const float* b2  = (const float*)d_in[6];
  const float* W3  = (const float*)d_in[7];
  const float* b3  = (const float*)d_in[8];
  const float* tkw = (const float*)d_in[9];
  const float* fcW = (const float*)d_in[10];
  const float* fcb = (const float*)d_in[11];
  const float* l1W = (const float*)d_in[12];
  const float* l1b = (const float*)d_in[13];
  const float* l2W = (const float*)d_in[14];
  const float* l2b = (const float*)d_in[15];
  float* out = (float*)d_out;

  char* ws = (char*)d_ws;
  size_t off = 0;
  auto alloc = [&](size_t bytes) {
    char* p = ws + off;
    off += (bytes + 255) & ~(size_t)255;
    return p;
  };
  // zero-init region (contiguous): cnt, fillc, rank, hpre
  int*   cnt   = (int*)alloc(15136 * 4);
  int*   fillc = (int*)alloc(15136 * 4);
  int*   rank  = (int*)alloc(121088 * 4);
  float* hpre  = (float*)alloc(4096 * 4);
  int*   rowstart = (int*)alloc(15136 * 4);
  float* dinv  = (float*)alloc(15136 * 4);
  float* scal  = (float*)alloc(64);
  float* z     = (float*)alloc((size_t)BSZ * K_TOP * 4);
  float* score = (float*)alloc(121088 * 4);
  float* d2a   = (float*)alloc(121088 * 4);
  unsigned long long* keys = (unsigned long long*)alloc(121088 * 8);
  int2*  csr   = (int2*)alloc((size_t)E_N * 8);
  float* hw = (float*)alloc((size_t)BSZ * N_G * NH * 4);
  float* h1 = (float*)alloc((size_t)BSZ * N_G * NH * 4);
  float* h2 = (float*)alloc((size_t)BSZ * N_G * NH * 4);
  float* h3 = (float*)alloc((size_t)BSZ * N_G * NH * 4);
  (void)ws_size; (void)in_sizes; (void)n_in; (void)out_size;

  int zero_n = (int)(((char*)rowstart - (char*)cnt) / 4);
  zero_kernel<<<(zero_n + 1023) / 1024, 1024, 0, stream>>>(cnt, zero_n);
  count_kernel<<<(E_N + 255) / 256, 256, 0, stream>>>(ei, cnt);
  dinv_kernel<<<(N_G + 255) / 256, 256, 0, stream>>>(cnt, dinv);
  prefix_kernel<<<1, 1024, 0, stream>>>(cnt, rowstart, tkw, scal);
  fill_kernel<<<(E_N + 255) / 256, 256, 0, stream>>>(ei, rowstart, dinv, fillc, csr);

  int M = BSZ * N_G;
  dim3 mmg((M + 63) / 64);
  int aggblocks = 8 * ((N_G + 3) / 4);

  mm_kernel<64><<<mmg, 128, 0, stream>>>(x, W1, hw, M);
  agg_kernel<<<aggblocks, 256, 0, stream>>>(hw, csr, rowstart, dinv, b1, h1);
  mm_kernel<128><<<mmg, 128, 0, stream>>>(h1, W2, hw, M);
  agg_kernel<<<aggblocks, 256, 0, stream>>>(hw, csr, rowstart, dinv, b2, h2);
  mm_kernel<128><<<mmg, 128, 0, stream>>>(h2, W3, hw, M);
  agg_kernel<<<aggblocks, 256, 0, stream>>>(hw, csr, rowstart, dinv, b3, h3);

  dim3 sg((N_G + 7) / 8, BSZ);
  score_kernel<<<sg, 256, 0, stream>>>(h1, h2, h3, tkw, fcW, scal, keys, score, d2a);
  dim3 rg(128, BSZ);
  rank_kernel<<<rg, 256, 0, stream>>>(keys, rank);
  dim3 scg((N_G + 255) / 256, BSZ);
  scat_kernel<<<scg, 256, 0, stream>>>(rank, score, d2a, fcb, z);
  dim3 l1g(32, BSZ);
  lin1_kernel<<<l1g, 256, 0, stream>>>(z, l1W, hpre);
  lin2_kernel<<<BSZ, 128, 0, stream>>>(hpre, l1b, l2W, l2b, out);
}

// Round 3
// 867.293 us; speedup vs baseline: 1.7614x; 1.0266x over previous
//
#include <hip/hip_runtime.h>

#define N_G   15135
#define E_N   242160
#define BSZ   8
#define K_TOP 7568
#define NH    128

// ---------------- utility ----------------
__global__ void zero_kernel(int* __restrict__ p, int n) {
  int i = blockIdx.x * 1024 + threadIdx.x;
  if (i < n) p[i] = 0;
}

__global__ void count_kernel(const int* __restrict__ ei, int* __restrict__ cnt) {
  int e = blockIdx.x * 256 + threadIdx.x;
  if (e < E_N) atomicAdd(&cnt[ei[E_N + e]], 1);
}

// per-chunk local scan + atomic ticket for block base (CSR rows may be laid out in any
// order across chunks; agg uses cnt[d] for length, never rowstart[d+1]).
// Also computes dinv and 1/||topk_w||.
__global__ __launch_bounds__(1024) void scan_kernel(const int* __restrict__ cnt,
                                                    int* __restrict__ rowstart,
                                                    float* __restrict__ dinv,
                                                    int* __restrict__ gctr,
                                                    const float* __restrict__ topk_w,
                                                    float* __restrict__ scal) {
  __shared__ int buf[1024];
  __shared__ int base;
  int tid = threadIdx.x;
  int i = blockIdx.x * 1024 + tid;
  int v = (i < N_G) ? cnt[i] : 0;
  if (i < N_G) dinv[i] = 1.0f / sqrtf((float)(v + 1));  // +1 = self loop
  buf[tid] = v;
  __syncthreads();
  for (int s = 1; s < 1024; s <<= 1) {
    int t = (tid >= s) ? buf[tid - s] : 0;
    __syncthreads();
    buf[tid] += t;
    __syncthreads();
  }
  if (tid == 1023) base = atomicAdd(gctr, buf[1023]);
  __syncthreads();
  if (i < N_G) rowstart[i] = base + buf[tid] - v;
  if (blockIdx.x == 0) {
    __shared__ float fbuf[512];
    if (tid < 512) {
      float w = (tid < 384) ? topk_w[tid] : 0.f;
      fbuf[tid] = w * w;
    }
    __syncthreads();
    for (int s = 256; s > 0; s >>= 1) {
      if (tid < s) fbuf[tid] += fbuf[tid + s];
      __syncthreads();
    }
    if (tid == 0) scal[0] = 1.0f / sqrtf(fbuf[0]);
  }
}

__global__ void fill_kernel(const int* __restrict__ ei, const int* __restrict__ rowstart,
                            const float* __restrict__ dinv, int* __restrict__ fillc,
                            int2* __restrict__ csr) {
  int e = blockIdx.x * 256 + threadIdx.x;
  if (e < E_N) {
    int s = ei[e], d = ei[E_N + e];
    int pos = rowstart[d] + atomicAdd(&fillc[d], 1);
    csr[pos] = make_int2(s, __float_as_int(dinv[s]));
  }
}

// ---------------- dense matmul: out[M][128] = A[M][CIN] @ W[CIN][128] ----------------
template<int CIN>
__global__ __launch_bounds__(128) void mm_kernel(const float* __restrict__ A,
                                                 const float* __restrict__ W,
                                                 float* __restrict__ out, int M) {
  __shared__ float Ast[32][68];
  int tid = threadIdx.x;
  int rb0 = blockIdx.x * 64;
  int c0 = (tid & 15) * 8;
  int r0 = (tid >> 4) * 8;
  float acc[8][8];
#pragma unroll
  for (int i = 0; i < 8; i++)
#pragma unroll
    for (int j = 0; j < 8; j++) acc[i][j] = 0.f;

  for (int k0 = 0; k0 < CIN; k0 += 32) {
#pragma unroll
    for (int q0 = 0; q0 < 512; q0 += 128) {
      int q = q0 + tid;
      int kk4 = (q & 7) * 4, r = q >> 3;
      int row = rb0 + r;
      float4 v = make_float4(0.f, 0.f, 0.f, 0.f);
      if (row < M) v = *(const float4*)(A + (size_t)row * CIN + k0 + kk4);
      Ast[kk4 + 0][r] = v.x; Ast[kk4 + 1][r] = v.y;
      Ast[kk4 + 2][r] = v.z; Ast[kk4 + 3][r] = v.w;
    }
    __syncthreads();
#pragma unroll 4
    for (int kk = 0; kk < 32; ++kk) {
      float a[8], b[8];
      *(float4*)&a[0] = *(const float4*)&Ast[kk][r0];
      *(float4*)&a[4] = *(const float4*)&Ast[kk][r0 + 4];
      const float* wr = W + (k0 + kk) * NH + c0;
      *(float4*)&b[0] = *(const float4*)(wr);
      *(float4*)&b[4] = *(const float4*)(wr + 4);
#pragma unroll
      for (int i = 0; i < 8; i++)
#pragma unroll
        for (int j = 0; j < 8; j++)
          acc[i][j] = fmaf(a[i], b[j], acc[i][j]);
    }
    __syncthreads();
  }
#pragma unroll
  for (int i = 0; i < 8; i++) {
    int row = rb0 + r0 + i;
    if (row < M) {
      *(float4*)(out + (size_t)row * NH + c0)     = make_float4(acc[i][0], acc[i][1], acc[i][2], acc[i][3]);
      *(float4*)(out + (size_t)row * NH + c0 + 4) = make_float4(acc[i][4], acc[i][5], acc[i][6], acc[i][7]);
    }
  }
}

// ---------------- sparse aggregation + bias + relu (all 128 channels) ----------------
__global__ __launch_bounds__(256) void agg_kernel(const float* __restrict__ hw,
                                                  const int2* __restrict__ csr,
                                                  const int* __restrict__ rowstart,
                                                  const int* __restrict__ cnt,
                                                  const float* __restrict__ dinv,
                                                  const float* __restrict__ bias,
                                                  float* __restrict__ hout) {
  int b = blockIdx.x & 7;
  int chunk = blockIdx.x >> 3;
  int wave = threadIdx.x >> 6, lane = threadIdx.x & 63;
  int d = chunk * 4 + wave;
  if (d >= N_G) return;
  const float2* hwb = (const float2*)(hw + (size_t)b * N_G * NH);
  float dv = dinv[d];
  int e0 = rowstart[d];
  int n = cnt[d];
  float2 vd = hwb[(size_t)d * 64 + lane];
  float a0x = dv * vd.x, a0y = dv * vd.y;
  float a1x = 0.f, a1y = 0.f, a2x = 0.f, a2y = 0.f, a3x = 0.f, a3y = 0.f;
  for (int l0 = 0; l0 < n; l0 += 64) {
    int idx = l0 + lane;
    int2 p = make_int2(0, 0);
    if (idx < n) p = csr[e0 + idx];
    int m = n - l0; if (m > 64) m = 64;
    int l = 0;
    for (; l + 4 <= m; l += 4) {
      int   s0 = __shfl(p.x, l + 0), s1 = __shfl(p.x, l + 1);
      int   s2 = __shfl(p.x, l + 2), s3 = __shfl(p.x, l + 3);
      float w0 = __int_as_float(__shfl(p.y, l + 0));
      float w1 = __int_as_float(__shfl(p.y, l + 1));
      float w2 = __int_as_float(__shfl(p.y, l + 2));
      float w3 = __int_as_float(__shfl(p.y, l + 3));
      float2 v0 = hwb[(size_t)s0 * 64 + lane];
      float2 v1 = hwb[(size_t)s1 * 64 + lane];
      float2 v2 = hwb[(size_t)s2 * 64 + lane];
      float2 v3 = hwb[(size_t)s3 * 64 + lane];
      a0x = fmaf(w0, v0.x, a0x); a0y = fmaf(w0, v0.y, a0y);
      a1x = fmaf(w1, v1.x, a1x); a1y = fmaf(w1, v1.y, a1y);
      a2x = fmaf(w2, v2.x, a2x); a2y = fmaf(w2, v2.y, a2y);
      a3x = fmaf(w3, v3.x, a3x); a3y = fmaf(w3, v3.y, a3y);
    }
    for (; l < m; ++l) {
      int   s = __shfl(p.x, l);
      float w = __int_as_float(__shfl(p.y, l));
      float2 v = hwb[(size_t)s * 64 + lane];
      a0x = fmaf(w, v.x, a0x); a0y = fmaf(w, v.y, a0y);
    }
  }
  float sx = a0x + a1x + a2x + a3x;
  float sy = a0y + a1y + a2y + a3y;
  float2 bb = ((const float2*)bias)[lane];
  float2 r;
  r.x = fmaxf(fmaf(dv, sx, bb.x), 0.f);
  r.y = fmaxf(fmaf(dv, sy, bb.y), 0.f);
  ((float2*)hout)[((size_t)b * N_G + d) * 64 + lane] = r;
}

// ---------------- layer-3 aggregation fused with score/key/fc-dot (h3 never stored) ----
// xc feature order: f = h*3 + layer. Lane holds channels c0=2*lane (f=6l+{0,1,2}) and
// c1=2*lane+1 (f=6l+{3,4,5}); layer0=h1, layer1=h2, layer2=h3(computed here).
__global__ __launch_bounds__(256) void agg_score_kernel(const float* __restrict__ hw,
                                                        const int2* __restrict__ csr,
                                                        const int* __restrict__ rowstart,
                                                        const int* __restrict__ cnt,
                                                        const float* __restrict__ dinv,
                                                        const float* __restrict__ bias,
                                                        const float* __restrict__ h1,
                                                        const float* __restrict__ h2,
                                                        const float* __restrict__ topk_w,
                                                        const float* __restrict__ fcW,
                                                        const float* __restrict__ scal,
                                                        unsigned long long* __restrict__ keys,
                                                        float* __restrict__ score,
                                                        float* __restrict__ d2a) {
  int b = blockIdx.x & 7;
  int chunk = blockIdx.x >> 3;
  int wave = threadIdx.x >> 6, lane = threadIdx.x & 63;
  int d = chunk * 4 + wave;
  if (d >= N_G) return;
  const float2* hwb = (const float2*)(hw + (size_t)b * N_G * NH);
  float dv = dinv[d];
  int e0 = rowstart[d];
  int n = cnt[d];
  float2 vd = hwb[(size_t)d * 64 + lane];
  float a0x = dv * vd.x, a0y = dv * vd.y;
  float a1x = 0.f, a1y = 0.f, a2x = 0.f, a2y = 0.f, a3x = 0.f, a3y = 0.f;
  for (int l0 = 0; l0 < n; l0 += 64) {
    int idx = l0 + lane;
    int2 p = make_int2(0, 0);
    if (idx < n) p = csr[e0 + idx];
    int m = n - l0; if (m > 64) m = 64;
    int l = 0;
    for (; l + 4 <= m; l += 4) {
      int   s0 = __shfl(p.x, l + 0), s1 = __shfl(p.x, l + 1);
      int   s2 = __shfl(p.x, l + 2), s3 = __shfl(p.x, l + 3);
      float w0 = __int_as_float(__shfl(p.y, l + 0));
      float w1 = __int_as_float(__shfl(p.y, l + 1));
      float w2 = __int_as_float(__shfl(p.y, l + 2));
      float w3 = __int_as_float(__shfl(p.y, l + 3));
      float2 v0 = hwb[(size_t)s0 * 64 + lane];
      float2 v1 = hwb[(size_t)s1 * 64 + lane];
      float2 v2 = hwb[(size_t)s2 * 64 + lane];
      float2 v3 = hwb[(size_t)s3 * 64 + lane];
      a0x = fmaf(w0, v0.x, a0x); a0y = fmaf(w0, v0.y, a0y);
      a1x = fmaf(w1, v1.x, a1x); a1y = fmaf(w1, v1.y, a1y);
      a2x = fmaf(w2, v2.x, a2x); a2y = fmaf(w2, v2.y, a2y);
      a3x = fmaf(w3, v3.x, a3x); a3y = fmaf(w3, v3.y, a3y);
    }
    for (; l < m; ++l) {
      int   s = __shfl(p.x, l);
      float w = __int_as_float(__shfl(p.y, l));
      float2 v = hwb[(size_t)s * 64 + lane];
      a0x = fmaf(w, v.x, a0x); a0y = fmaf(w, v.y, a0y);
    }
  }
  float sx = a0x + a1x + a2x + a3x;
  float sy = a0y + a1y + a2y + a3y;
  float2 bb = ((const float2*)bias)[lane];
  float2 r;
  r.x = fmaxf(fmaf(dv, sx, bb.x), 0.f);
  r.y = fmaxf(fmaf(dv, sy, bb.y), 0.f);
  // fused score: read h1,h2 rows, dot with topk_w and fcW in xc order
  size_t rbase = ((size_t)b * N_G + d) * 64 + lane;
  float2 u1 = ((const float2*)h1)[rbase];
  float2 u2 = ((const float2*)h2)[rbase];
  const float2* tw2 = (const float2*)topk_w;
  const float2* fw2 = (const float2*)fcW;
  float2 ta = tw2[lane * 3 + 0], tb = tw2[lane * 3 + 1], tc = tw2[lane * 3 + 2];
  float2 fa = fw2[lane * 3 + 0], fb = fw2[lane * 3 + 1], fc = fw2[lane * 3 + 2];
  float d1 = u1.x * ta.x + u2.x * ta.y + r.x * tb.x
           + u1.y * tb.y + u2.y * tc.x + r.y * tc.y;
  float d2 = u1.x * fa.x + u2.x * fa.y + r.x * fb.x
           + u1.y * fb.y + u2.y * fc.x + r.y * fc.y;
#pragma unroll
  for (int s = 32; s > 0; s >>= 1) {
    d1 += __shfl_down(d1, s);
    d2 += __shfl_down(d2, s);
  }
  if (lane == 0) {
    int gw = b * N_G + d;
    float sc = tanhf(d1 * scal[0]);
    score[gw] = sc;
    d2a[gw] = d2;
    unsigned int u = __float_as_uint(sc);
    unsigned int k32 = (u & 0x80000000u) ? ~u : (u | 0x80000000u);  // monotone float->u32
    keys[gw] = ((unsigned long long)k32 << 32) | (unsigned long long)(0xFFFFFFFFu - (unsigned)d);
  }
}

// ---------------- exact descending rank: VGPR i-keys vs scalar-broadcast j-keys ----------
#define RANK_JCH 1896  // 8*237
__global__ __launch_bounds__(256) void rank_kernel(const unsigned long long* __restrict__ keys,
                                                   int* __restrict__ rank) {
  int b = blockIdx.y;
  int ib = blockIdx.x >> 3;   // 0..7  i-blocks of 2048
  int js = blockIdx.x & 7;    // 0..7  j-splits of RANK_JCH
  const unsigned long long* kb = keys + (size_t)b * N_G;
  int tid = threadIdx.x;
  int i0 = ib * 2048 + tid;
  unsigned long long ki[8];
  int cnt[8];
#pragma unroll
  for (int t = 0; t < 8; t++) {
    int i = i0 + t * 256;
    ki[t] = (i < N_G) ? kb[i] : ~0ull;
    cnt[t] = 0;
  }
  int j0 = js * RANK_JCH;
  int j1 = j0 + RANK_JCH; if (j1 > N_G) j1 = N_G;
  int j = j0;
  for (; j + 8 <= j1; j += 8) {
    unsigned long long k0 = kb[j + 0], k1 = kb[j + 1], k2 = kb[j + 2], k3 = kb[j + 3];
    unsigned long long k4 = kb[j + 4], k5 = kb[j + 5], k6 = kb[j + 6], k7 = kb[j + 7];
#pragma unroll
    for (int t = 0; t < 8; t++) {
      int c = (k0 > ki[t]) + (k1 > ki[t]) + (k2 > ki[t]) + (k3 > ki[t])
            + (k4 > ki[t]) + (k5 > ki[t]) + (k6 > ki[t]) + (k7 > ki[t]);
      cnt[t] += c;
    }
  }
  for (; j < j1; ++j) {
    unsigned long long kj = kb[j];
#pragma unroll
    for (int t = 0; t < 8; t++) cnt[t] += (kj > ki[t]) ? 1 : 0;
  }
#pragma unroll
  for (int t = 0; t < 8; t++) {
    int i = i0 + t * 256;
    if (i < N_G && cnt[t] > 0) atomicAdd(&rank[b * N_G + i], cnt[t]);
  }
}

__global__ void scat_kernel(const int* __restrict__ rank, const float* __restrict__ score,
                            const float* __restrict__ d2a, const float* __restrict__ fcb,
                            float* __restrict__ z) {
  int b = blockIdx.y;
  int i = blockIdx.x * 256 + threadIdx.x;
  if (i < N_G) {
    int r = rank[b * N_G + i];
    if (r < K_TOP) z[b * K_TOP + r] = fmaf(score[b * N_G + i], d2a[b * N_G + i], fcb[0]);
  }
}

// ---------------- lin1: hpre[b][c] += sum_r z[b][r]*W[r][c] (r-split + atomics) ----------------
__global__ __launch_bounds__(256) void lin1_kernel(const float* __restrict__ z,
                                                   const float* __restrict__ W,
                                                   float* __restrict__ hpre) {
  __shared__ float zb[237];
  int b = blockIdx.y, rs = blockIdx.x;
  int r0 = rs * 237;
  int rn = K_TOP - r0; if (rn > 237) rn = 237;
  for (int q = threadIdx.x; q < rn; q += 256) zb[q] = z[b * K_TOP + r0 + q];
  __syncthreads();
  int c = threadIdx.x;
  float a0 = 0.f, a1 = 0.f;
  for (int r = 0; r < rn; ++r) {
    float zz = zb[r];
    const float* wr = W + (size_t)(r0 + r) * 512;
    a0 = fmaf(zz, wr[c], a0);
    a1 = fmaf(zz, wr[c + 256], a1);
  }
  atomicAdd(&hpre[b * 512 + c], a0);
  atomicAdd(&hpre[b * 512 + c + 256], a1);
}

// ---------------- lin2 + log_softmax ----------------
__global__ __launch_bounds__(128) void lin2_kernel(const float* __restrict__ hpre,
                                                   const float* __restrict__ l1b,
                                                   const float* __restrict__ W2,
                                                   const float* __restrict__ l2b,
                                                   float* __restrict__ out) {
  int b = blockIdx.x, tid = threadIdx.x;
  float a0 = 0.f, a1 = 0.f;
  for (int j = tid; j < 512; j += 128) {
    float t = fmaxf(hpre[b * 512 + j] + l1b[j], 0.f);
    a0 = fmaf(t, W2[j * 2 + 0], a0);
    a1 = fmaf(t, W2[j * 2 + 1], a1);
  }
#pragma unroll
  for (int s = 32; s > 0; s >>= 1) {
    a0 += __shfl_down(a0, s);
    a1 += __shfl_down(a1, s);
  }
  __shared__ float red[2][2];
  if ((tid & 63) == 0) { red[tid >> 6][0] = a0; red[tid >> 6][1] = a1; }
  __syncthreads();
  if (tid == 0) {
    float l0 = red[0][0] + red[1][0] + l2b[0];
    float l1 = red[0][1] + red[1][1] + l2b[1];
    float m = fmaxf(l0, l1);
    float lse = m + logf(expf(l0 - m) + expf(l1 - m));
    out[b * 2 + 0] = l0 - lse;
    out[b * 2 + 1] = l1 - lse;
  }
}

extern "C" void kernel_launch(void* const* d_in, const int* in_sizes, int n_in,
                              void* d_out, int out_size, void* d_ws, size_t ws_size,
                              hipStream_t stream) {
  const float* x   = (const float*)d_in[0];
  const int*   ei  = (const int*)d_in[2];
  const float* W1  = (const float*)d_in[3];
  const float* b1  = (const float*)d_in[4];
  const float* W2  = (const float*)d_in[5];
  const float* b2  = (const float*)d_in[6];
  const float* W3  = (const float*)d_in[7];
  const float* b3  = (const float*)d_in[8];
  const float* tkw = (const float*)d_in[9];
  const float* fcW = (const float*)d_in[10];
  const float* fcb = (const float*)d_in[11];
  const float* l1W = (const float*)d_in[12];
  const float* l1b = (const float*)d_in[13];
  const float* l2W = (const float*)d_in[14];
  const float* l2b = (const float*)d_in[15];
  float* out = (float*)d_out;

  char* ws = (char*)d_ws;
  size_t off = 0;
  auto alloc = [&](size_t bytes) {
    char* p = ws + off;
    off += (bytes + 255) & ~(size_t)255;
    return p;
  };
  // zero-init region (contiguous): cnt, fillc, gctr, rank, hpre
  int*   cnt   = (int*)alloc(15136 * 4);
  int*   fillc = (int*)alloc(15136 * 4);
  int*   gctr  = (int*)alloc(256);
  int*   rank  = (int*)alloc(121088 * 4);
  float* hpre  = (float*)alloc(4096 * 4);
  int*   rowstart = (int*)alloc(15136 * 4);
  float* dinv  = (float*)alloc(15136 * 4);
  float* scal  = (float*)alloc(64);
  float* z     = (float*)alloc((size_t)BSZ * K_TOP * 4);
  float* score = (float*)alloc(121088 * 4);
  float* d2a   = (float*)alloc(121088 * 4);
  unsigned long long* keys = (unsigned long long*)alloc(121088 * 8);
  int2*  csr   = (int2*)alloc((size_t)E_N * 8);
  float* hw = (float*)alloc((size_t)BSZ * N_G * NH * 4);
  float* h1 = (float*)alloc((size_t)BSZ * N_G * NH * 4);
  float* h2 = (float*)alloc((size_t)BSZ * N_G * NH * 4);
  (void)ws_size; (void)in_sizes; (void)n_in; (void)out_size;

  int zero_n = (int)(((char*)rowstart - (char*)cnt) / 4);
  zero_kernel<<<(zero_n + 1023) / 1024, 1024, 0, stream>>>(cnt, zero_n);
  count_kernel<<<(E_N + 255) / 256, 256, 0, stream>>>(ei, cnt);
  scan_kernel<<<(N_G + 1023) / 1024, 1024, 0, stream>>>(cnt, rowstart, dinv, gctr, tkw, scal);
  fill_kernel<<<(E_N + 255) / 256, 256, 0, stream>>>(ei, rowstart, dinv, fillc, csr);

  int M = BSZ * N_G;
  dim3 mmg((M + 63) / 64);
  int aggblocks = 8 * ((N_G + 3) / 4);

  mm_kernel<64><<<mmg, 128, 0, stream>>>(x, W1, hw, M);
  agg_kernel<<<aggblocks, 256, 0, stream>>>(hw, csr, rowstart, cnt, dinv, b1, h1);
  mm_kernel<128><<<mmg, 128, 0, stream>>>(h1, W2, hw, M);
  agg_kernel<<<aggblocks, 256, 0, stream>>>(hw, csr, rowstart, cnt, dinv, b2, h2);
  mm_kernel<128><<<mmg, 128, 0, stream>>>(h2, W3, hw, M);
  agg_score_kernel<<<aggblocks, 256, 0, stream>>>(hw, csr, rowstart, cnt, dinv, b3,
                                                  h1, h2, tkw, fcW, scal, keys, score, d2a);

  dim3 rg(64, BSZ);
  rank_kernel<<<rg, 256, 0, stream>>>(keys, rank);
  dim3 scg((N_G + 255) / 256, BSZ);
  scat_kernel<<<scg, 256, 0, stream>>>(rank, score, d2a, fcb, z);
  dim3 l1g(32, BSZ);
  lin1_kernel<<<l1g, 256, 0, stream>>>(z, l1W, hpre);
  lin2_kernel<<<BSZ, 128, 0, stream>>>(hpre, l1b, l2W, l2b, out);
}

// Round 4
// 846.218 us; speedup vs baseline: 1.8053x; 1.0249x over previous
//
#include <hip/hip_runtime.h>

#define N_G   15135
#define E_N   242160
#define BSZ   8
#define K_TOP 7568
#define NH    128

// ---------------- utility ----------------
__global__ void zero_kernel(int* __restrict__ p, int n) {
  int i = blockIdx.x * 1024 + threadIdx.x;
  if (i < n) p[i] = 0;
}

__global__ void count_kernel(const int* __restrict__ ei, int* __restrict__ cnt) {
  int e = blockIdx.x * 256 + threadIdx.x;
  if (e < E_N) atomicAdd(&cnt[ei[E_N + e]], 1);
}

// per-chunk local scan + atomic ticket for block base (CSR rows may be laid out in any
// order across chunks; agg uses cnt[d] for length, never rowstart[d+1]).
// Also computes dinv and 1/||topk_w||.
__global__ __launch_bounds__(1024) void scan_kernel(const int* __restrict__ cnt,
                                                    int* __restrict__ rowstart,
                                                    float* __restrict__ dinv,
                                                    int* __restrict__ gctr,
                                                    const float* __restrict__ topk_w,
                                                    float* __restrict__ scal) {
  __shared__ int buf[1024];
  __shared__ int base;
  int tid = threadIdx.x;
  int i = blockIdx.x * 1024 + tid;
  int v = (i < N_G) ? cnt[i] : 0;
  if (i < N_G) dinv[i] = 1.0f / sqrtf((float)(v + 1));  // +1 = self loop
  buf[tid] = v;
  __syncthreads();
  for (int s = 1; s < 1024; s <<= 1) {
    int t = (tid >= s) ? buf[tid - s] : 0;
    __syncthreads();
    buf[tid] += t;
    __syncthreads();
  }
  if (tid == 1023) base = atomicAdd(gctr, buf[1023]);
  __syncthreads();
  if (i < N_G) rowstart[i] = base + buf[tid] - v;
  if (blockIdx.x == 0) {
    __shared__ float fbuf[512];
    if (tid < 512) {
      float w = (tid < 384) ? topk_w[tid] : 0.f;
      fbuf[tid] = w * w;
    }
    __syncthreads();
    for (int s = 256; s > 0; s >>= 1) {
      if (tid < s) fbuf[tid] += fbuf[tid + s];
      __syncthreads();
    }
    if (tid == 0) scal[0] = 1.0f / sqrtf(fbuf[0]);
  }
}

__global__ void fill_kernel(const int* __restrict__ ei, const int* __restrict__ rowstart,
                            const float* __restrict__ dinv, int* __restrict__ fillc,
                            int2* __restrict__ csr) {
  int e = blockIdx.x * 256 + threadIdx.x;
  if (e < E_N) {
    int s = ei[e], d = ei[E_N + e];
    int pos = rowstart[d] + atomicAdd(&fillc[d], 1);
    csr[pos] = make_int2(s, __float_as_int(dinv[s]));
  }
}

// ---------------- dense matmul: out[M][128] = A[M][CIN] @ W[CIN][128] ----------------
template<int CIN>
__global__ __launch_bounds__(128) void mm_kernel(const float* __restrict__ A,
                                                 const float* __restrict__ W,
                                                 float* __restrict__ out, int M) {
  __shared__ float Ast[32][68];
  int tid = threadIdx.x;
  int rb0 = blockIdx.x * 64;
  int c0 = (tid & 15) * 8;
  int r0 = (tid >> 4) * 8;
  float acc[8][8];
#pragma unroll
  for (int i = 0; i < 8; i++)
#pragma unroll
    for (int j = 0; j < 8; j++) acc[i][j] = 0.f;

  for (int k0 = 0; k0 < CIN; k0 += 32) {
#pragma unroll
    for (int q0 = 0; q0 < 512; q0 += 128) {
      int q = q0 + tid;
      int kk4 = (q & 7) * 4, r = q >> 3;
      int row = rb0 + r;
      float4 v = make_float4(0.f, 0.f, 0.f, 0.f);
      if (row < M) v = *(const float4*)(A + (size_t)row * CIN + k0 + kk4);
      Ast[kk4 + 0][r] = v.x; Ast[kk4 + 1][r] = v.y;
      Ast[kk4 + 2][r] = v.z; Ast[kk4 + 3][r] = v.w;
    }
    __syncthreads();
#pragma unroll 4
    for (int kk = 0; kk < 32; ++kk) {
      float a[8], b[8];
      *(float4*)&a[0] = *(const float4*)&Ast[kk][r0];
      *(float4*)&a[4] = *(const float4*)&Ast[kk][r0 + 4];
      const float* wr = W + (k0 + kk) * NH + c0;
      *(float4*)&b[0] = *(const float4*)(wr);
      *(float4*)&b[4] = *(const float4*)(wr + 4);
#pragma unroll
      for (int i = 0; i < 8; i++)
#pragma unroll
        for (int j = 0; j < 8; j++)
          acc[i][j] = fmaf(a[i], b[j], acc[i][j]);
    }
    __syncthreads();
  }
#pragma unroll
  for (int i = 0; i < 8; i++) {
    int row = rb0 + r0 + i;
    if (row < M) {
      *(float4*)(out + (size_t)row * NH + c0)     = make_float4(acc[i][0], acc[i][1], acc[i][2], acc[i][3]);
      *(float4*)(out + (size_t)row * NH + c0 + 4) = make_float4(acc[i][4], acc[i][5], acc[i][6], acc[i][7]);
    }
  }
}

// ---------------- sparse aggregation + bias + relu (all 128 channels) ----------------
__global__ __launch_bounds__(256) void agg_kernel(const float* __restrict__ hw,
                                                  const int2* __restrict__ csr,
                                                  const int* __restrict__ rowstart,
                                                  const int* __restrict__ cnt,
                                                  const float* __restrict__ dinv,
                                                  const float* __restrict__ bias,
                                                  float* __restrict__ hout) {
  int b = blockIdx.x & 7;
  int chunk = blockIdx.x >> 3;
  int wave = threadIdx.x >> 6, lane = threadIdx.x & 63;
  int d = chunk * 4 + wave;
  if (d >= N_G) return;
  const float2* hwb = (const float2*)(hw + (size_t)b * N_G * NH);
  float dv = dinv[d];
  int e0 = rowstart[d];
  int n = cnt[d];
  float2 vd = hwb[(size_t)d * 64 + lane];
  float a0x = dv * vd.x, a0y = dv * vd.y;
  float a1x = 0.f, a1y = 0.f, a2x = 0.f, a2y = 0.f, a3x = 0.f, a3y = 0.f;
  for (int l0 = 0; l0 < n; l0 += 64) {
    int idx = l0 + lane;
    int2 p = make_int2(0, 0);
    if (idx < n) p = csr[e0 + idx];
    int m = n - l0; if (m > 64) m = 64;
    int l = 0;
    for (; l + 4 <= m; l += 4) {
      int   s0 = __shfl(p.x, l + 0), s1 = __shfl(p.x, l + 1);
      int   s2 = __shfl(p.x, l + 2), s3 = __shfl(p.x, l + 3);
      float w0 = __int_as_float(__shfl(p.y, l + 0));
      float w1 = __int_as_float(__shfl(p.y, l + 1));
      float w2 = __int_as_float(__shfl(p.y, l + 2));
      float w3 = __int_as_float(__shfl(p.y, l + 3));
      float2 v0 = hwb[(size_t)s0 * 64 + lane];
      float2 v1 = hwb[(size_t)s1 * 64 + lane];
      float2 v2 = hwb[(size_t)s2 * 64 + lane];
      float2 v3 = hwb[(size_t)s3 * 64 + lane];
      a0x = fmaf(w0, v0.x, a0x); a0y = fmaf(w0, v0.y, a0y);
      a1x = fmaf(w1, v1.x, a1x); a1y = fmaf(w1, v1.y, a1y);
      a2x = fmaf(w2, v2.x, a2x); a2y = fmaf(w2, v2.y, a2y);
      a3x = fmaf(w3, v3.x, a3x); a3y = fmaf(w3, v3.y, a3y);
    }
    for (; l < m; ++l) {
      int   s = __shfl(p.x, l);
      float w = __int_as_float(__shfl(p.y, l));
      float2 v = hwb[(size_t)s * 64 + lane];
      a0x = fmaf(w, v.x, a0x); a0y = fmaf(w, v.y, a0y);
    }
  }
  float sx = a0x + a1x + a2x + a3x;
  float sy = a0y + a1y + a2y + a3y;
  float2 bb = ((const float2*)bias)[lane];
  float2 r;
  r.x = fmaxf(fmaf(dv, sx, bb.x), 0.f);
  r.y = fmaxf(fmaf(dv, sy, bb.y), 0.f);
  ((float2*)hout)[((size_t)b * N_G + d) * 64 + lane] = r;
}

// ---------------- layer-3 aggregation fused with score/key/fc-dot (h3 never stored) ----
__global__ __launch_bounds__(256) void agg_score_kernel(const float* __restrict__ hw,
                                                        const int2* __restrict__ csr,
                                                        const int* __restrict__ rowstart,
                                                        const int* __restrict__ cnt,
                                                        const float* __restrict__ dinv,
                                                        const float* __restrict__ bias,
                                                        const float* __restrict__ h1,
                                                        const float* __restrict__ h2,
                                                        const float* __restrict__ topk_w,
                                                        const float* __restrict__ fcW,
                                                        const float* __restrict__ scal,
                                                        unsigned long long* __restrict__ keys,
                                                        float* __restrict__ score,
                                                        float* __restrict__ d2a) {
  int b = blockIdx.x & 7;
  int chunk = blockIdx.x >> 3;
  int wave = threadIdx.x >> 6, lane = threadIdx.x & 63;
  int d = chunk * 4 + wave;
  if (d >= N_G) return;
  const float2* hwb = (const float2*)(hw + (size_t)b * N_G * NH);
  float dv = dinv[d];
  int e0 = rowstart[d];
  int n = cnt[d];
  float2 vd = hwb[(size_t)d * 64 + lane];
  float a0x = dv * vd.x, a0y = dv * vd.y;
  float a1x = 0.f, a1y = 0.f, a2x = 0.f, a2y = 0.f, a3x = 0.f, a3y = 0.f;
  for (int l0 = 0; l0 < n; l0 += 64) {
    int idx = l0 + lane;
    int2 p = make_int2(0, 0);
    if (idx < n) p = csr[e0 + idx];
    int m = n - l0; if (m > 64) m = 64;
    int l = 0;
    for (; l + 4 <= m; l += 4) {
      int   s0 = __shfl(p.x, l + 0), s1 = __shfl(p.x, l + 1);
      int   s2 = __shfl(p.x, l + 2), s3 = __shfl(p.x, l + 3);
      float w0 = __int_as_float(__shfl(p.y, l + 0));
      float w1 = __int_as_float(__shfl(p.y, l + 1));
      float w2 = __int_as_float(__shfl(p.y, l + 2));
      float w3 = __int_as_float(__shfl(p.y, l + 3));
      float2 v0 = hwb[(size_t)s0 * 64 + lane];
      float2 v1 = hwb[(size_t)s1 * 64 + lane];
      float2 v2 = hwb[(size_t)s2 * 64 + lane];
      float2 v3 = hwb[(size_t)s3 * 64 + lane];
      a0x = fmaf(w0, v0.x, a0x); a0y = fmaf(w0, v0.y, a0y);
      a1x = fmaf(w1, v1.x, a1x); a1y = fmaf(w1, v1.y, a1y);
      a2x = fmaf(w2, v2.x, a2x); a2y = fmaf(w2, v2.y, a2y);
      a3x = fmaf(w3, v3.x, a3x); a3y = fmaf(w3, v3.y, a3y);
    }
    for (; l < m; ++l) {
      int   s = __shfl(p.x, l);
      float w = __int_as_float(__shfl(p.y, l));
      float2 v = hwb[(size_t)s * 64 + lane];
      a0x = fmaf(w, v.x, a0x); a0y = fmaf(w, v.y, a0y);
    }
  }
  float sx = a0x + a1x + a2x + a3x;
  float sy = a0y + a1y + a2y + a3y;
  float2 bb = ((const float2*)bias)[lane];
  float2 r;
  r.x = fmaxf(fmaf(dv, sx, bb.x), 0.f);
  r.y = fmaxf(fmaf(dv, sy, bb.y), 0.f);
  // fused score: read h1,h2 rows, dot with topk_w and fcW in xc order (f = h*3 + layer)
  size_t rbase = ((size_t)b * N_G + d) * 64 + lane;
  float2 u1 = ((const float2*)h1)[rbase];
  float2 u2 = ((const float2*)h2)[rbase];
  const float2* tw2 = (const float2*)topk_w;
  const float2* fw2 = (const float2*)fcW;
  float2 ta = tw2[lane * 3 + 0], tb = tw2[lane * 3 + 1], tc = tw2[lane * 3 + 2];
  float2 fa = fw2[lane * 3 + 0], fb = fw2[lane * 3 + 1], fc = fw2[lane * 3 + 2];
  float d1 = u1.x * ta.x + u2.x * ta.y + r.x * tb.x
           + u1.y * tb.y + u2.y * tc.x + r.y * tc.y;
  float d2 = u1.x * fa.x + u2.x * fa.y + r.x * fb.x
           + u1.y * fb.y + u2.y * fc.x + r.y * fc.y;
#pragma unroll
  for (int s = 32; s > 0; s >>= 1) {
    d1 += __shfl_down(d1, s);
    d2 += __shfl_down(d2, s);
  }
  if (lane == 0) {
    int gw = b * N_G + d;
    float sc = tanhf(d1 * scal[0]);
    score[gw] = sc;
    d2a[gw] = d2;
    unsigned int u = __float_as_uint(sc);
    unsigned int k32 = (u & 0x80000000u) ? ~u : (u | 0x80000000u);  // monotone float->u32
    keys[gw] = ((unsigned long long)k32 << 32) | (unsigned long long)(0xFFFFFFFFu - (unsigned)d);
  }
}

// ---------------- exact descending rank: VGPR i-keys vs scalar-broadcast j-keys ----------
// grid x = ib(8) * js(32) -> 2048 blocks total = 8 blocks/CU (32 waves/CU, 100% slots).
#define RANK_JS  32
#define RANK_JCH 473  // ceil(15135/32)
__global__ __launch_bounds__(256) void rank_kernel(const unsigned long long* __restrict__ keys,
                                                   int* __restrict__ rank) {
  int b = blockIdx.y;
  int ib = blockIdx.x >> 5;          // 0..7  i-blocks of 2048
  int js = blockIdx.x & (RANK_JS-1); // 0..31 j-splits of RANK_JCH
  const unsigned long long* kb = keys + (size_t)b * N_G;
  int tid = threadIdx.x;
  int i0 = ib * 2048 + tid;
  unsigned long long ki[8];
  int cnt[8];
#pragma unroll
  for (int t = 0; t < 8; t++) {
    int i = i0 + t * 256;
    ki[t] = (i < N_G) ? kb[i] : ~0ull;
    cnt[t] = 0;
  }
  int j0 = js * RANK_JCH;
  int j1 = j0 + RANK_JCH; if (j1 > N_G) j1 = N_G;
  int j = j0;
  for (; j + 8 <= j1; j += 8) {
    unsigned long long k0 = kb[j + 0], k1 = kb[j + 1], k2 = kb[j + 2], k3 = kb[j + 3];
    unsigned long long k4 = kb[j + 4], k5 = kb[j + 5], k6 = kb[j + 6], k7 = kb[j + 7];
#pragma unroll
    for (int t = 0; t < 8; t++) {
      cnt[t] += (k0 > ki[t]); cnt[t] += (k1 > ki[t]);
      cnt[t] += (k2 > ki[t]); cnt[t] += (k3 > ki[t]);
      cnt[t] += (k4 > ki[t]); cnt[t] += (k5 > ki[t]);
      cnt[t] += (k6 > ki[t]); cnt[t] += (k7 > ki[t]);
    }
  }
  for (; j < j1; ++j) {
    unsigned long long kj = kb[j];
#pragma unroll
    for (int t = 0; t < 8; t++) cnt[t] += (kj > ki[t]) ? 1 : 0;
  }
#pragma unroll
  for (int t = 0; t < 8; t++) {
    int i = i0 + t * 256;
    if (i < N_G && cnt[t] > 0) atomicAdd(&rank[b * N_G + i], cnt[t]);
  }
}

__global__ void scat_kernel(const int* __restrict__ rank, const float* __restrict__ score,
                            const float* __restrict__ d2a, const float* __restrict__ fcb,
                            float* __restrict__ z) {
  int b = blockIdx.y;
  int i = blockIdx.x * 256 + threadIdx.x;
  if (i < N_G) {
    int r = rank[b * N_G + i];
    if (r < K_TOP) z[b * K_TOP + r] = fmaf(score[b * N_G + i], d2a[b * N_G + i], fcb[0]);
  }
}

// ---------------- lin1: hpre[b][c] += sum_r z[b][r]*W[r][c] (r-split + atomics) ----------------
__global__ __launch_bounds__(256) void lin1_kernel(const float* __restrict__ z,
                                                   const float* __restrict__ W,
                                                   float* __restrict__ hpre) {
  __shared__ float zb[237];
  int b = blockIdx.y, rs = blockIdx.x;
  int r0 = rs * 237;
  int rn = K_TOP - r0; if (rn > 237) rn = 237;
  for (int q = threadIdx.x; q < rn; q += 256) zb[q] = z[b * K_TOP + r0 + q];
  __syncthreads();
  int c = threadIdx.x;
  float a0 = 0.f, a1 = 0.f;
  for (int r = 0; r < rn; ++r) {
    float zz = zb[r];
    const float* wr = W + (size_t)(r0 + r) * 512;
    a0 = fmaf(zz, wr[c], a0);
    a1 = fmaf(zz, wr[c + 256], a1);
  }
  atomicAdd(&hpre[b * 512 + c], a0);
  atomicAdd(&hpre[b * 512 + c + 256], a1);
}

// ---------------- lin2 + log_softmax ----------------
__global__ __launch_bounds__(128) void lin2_kernel(const float* __restrict__ hpre,
                                                   const float* __restrict__ l1b,
                                                   const float* __restrict__ W2,
                                                   const float* __restrict__ l2b,
                                                   float* __restrict__ out) {
  int b = blockIdx.x, tid = threadIdx.x;
  float a0 = 0.f, a1 = 0.f;
  for (int j = tid; j < 512; j += 128) {
    float t = fmaxf(hpre[b * 512 + j] + l1b[j], 0.f);
    a0 = fmaf(t, W2[j * 2 + 0], a0);
    a1 = fmaf(t, W2[j * 2 + 1], a1);
  }
#pragma unroll
  for (int s = 32; s > 0; s >>= 1) {
    a0 += __shfl_down(a0, s);
    a1 += __shfl_down(a1, s);
  }
  __shared__ float red[2][2];
  if ((tid & 63) == 0) { red[tid >> 6][0] = a0; red[tid >> 6][1] = a1; }
  __syncthreads();
  if (tid == 0) {
    float l0 = red[0][0] + red[1][0] + l2b[0];
    float l1 = red[0][1] + red[1][1] + l2b[1];
    float m = fmaxf(l0, l1);
    float lse = m + logf(expf(l0 - m) + expf(l1 - m));
    out[b * 2 + 0] = l0 - lse;
    out[b * 2 + 1] = l1 - lse;
  }
}

extern "C" void kernel_launch(void* const* d_in, const int* in_sizes, int n_in,
                              void* d_out, int out_size, void* d_ws, size_t ws_size,
                              hipStream_t stream) {
  const float* x   = (const float*)d_in[0];
  const int*   ei  = (const int*)d_in[2];
  const float* W1  = (const float*)d_in[3];
  const float* b1  = (const float*)d_in[4];
  const float* W2  = (const float*)d_in[5];
  const float* b2  = (const float*)d_in[6];
  const float* W3  = (const float*)d_in[7];
  const float* b3  = (const float*)d_in[8];
  const float* tkw = (const float*)d_in[9];
  const float* fcW = (const float*)d_in[10];
  const float* fcb = (const float*)d_in[11];
  const float* l1W = (const float*)d_in[12];
  const float* l1b = (const float*)d_in[13];
  const float* l2W = (const float*)d_in[14];
  const float* l2b = (const float*)d_in[15];
  float* out = (float*)d_out;

  char* ws = (char*)d_ws;
  size_t off = 0;
  auto alloc = [&](size_t bytes) {
    char* p = ws + off;
    off += (bytes + 255) & ~(size_t)255;
    return p;
  };
  // zero-init region (contiguous): cnt, fillc, gctr, rank, hpre
  int*   cnt   = (int*)alloc(15136 * 4);
  int*   fillc = (int*)alloc(15136 * 4);
  int*   gctr  = (int*)alloc(256);
  int*   rank  = (int*)alloc(121088 * 4);
  float* hpre  = (float*)alloc(4096 * 4);
  int*   rowstart = (int*)alloc(15136 * 4);
  float* dinv  = (float*)alloc(15136 * 4);
  float* scal  = (float*)alloc(64);
  float* z     = (float*)alloc((size_t)BSZ * K_TOP * 4);
  float* score = (float*)alloc(121088 * 4);
  float* d2a   = (float*)alloc(121088 * 4);
  unsigned long long* keys = (unsigned long long*)alloc(121088 * 8);
  int2*  csr   = (int2*)alloc((size_t)E_N * 8);
  float* hw = (float*)alloc((size_t)BSZ * N_G * NH * 4);
  float* h1 = (float*)alloc((size_t)BSZ * N_G * NH * 4);
  float* h2 = (float*)alloc((size_t)BSZ * N_G * NH * 4);
  (void)ws_size; (void)in_sizes; (void)n_in; (void)out_size;

  int zero_n = (int)(((char*)rowstart - (char*)cnt) / 4);
  zero_kernel<<<(zero_n + 1023) / 1024, 1024, 0, stream>>>(cnt, zero_n);
  count_kernel<<<(E_N + 255) / 256, 256, 0, stream>>>(ei, cnt);
  scan_kernel<<<(N_G + 1023) / 1024, 1024, 0, stream>>>(cnt, rowstart, dinv, gctr, tkw, scal);
  fill_kernel<<<(E_N + 255) / 256, 256, 0, stream>>>(ei, rowstart, dinv, fillc, csr);

  int M = BSZ * N_G;
  dim3 mmg((M + 63) / 64);
  int aggblocks = 8 * ((N_G + 3) / 4);

  mm_kernel<64><<<mmg, 128, 0, stream>>>(x, W1, hw, M);
  agg_kernel<<<aggblocks, 256, 0, stream>>>(hw, csr, rowstart, cnt, dinv, b1, h1);
  mm_kernel<128><<<mmg, 128, 0, stream>>>(h1, W2, hw, M);
  agg_kernel<<<aggblocks, 256, 0, stream>>>(hw, csr, rowstart, cnt, dinv, b2, h2);
  mm_kernel<128><<<mmg, 128, 0, stream>>>(h2, W3, hw, M);
  agg_score_kernel<<<aggblocks, 256, 0, stream>>>(hw, csr, rowstart, cnt, dinv, b3,
                                                  h1, h2, tkw, fcW, scal, keys, score, d2a);

  dim3 rg(8 * RANK_JS, BSZ);
  rank_kernel<<<rg, 256, 0, stream>>>(keys, rank);
  dim3 scg((N_G + 255) / 256, BSZ);
  scat_kernel<<<scg, 256, 0, stream>>>(rank, score, d2a, fcb, z);
  dim3 l1g(32, BSZ);
  lin1_kernel<<<l1g, 256, 0, stream>>>(z, l1W, hpre);
  lin2_kernel<<<BSZ, 128, 0, stream>>>(hpre, l1b, l2W, l2b, out);
}

// Round 5
// 696.480 us; speedup vs baseline: 2.1934x; 1.2150x over previous
//
#include <hip/hip_runtime.h>

#define N_G   15135
#define E_N   242160
#define BSZ   8
#define K_TOP 7568
#define NH    128

// ---------------- utility ----------------
__global__ void zero_kernel(int* __restrict__ p, int n) {
  int i = blockIdx.x * 1024 + threadIdx.x;
  if (i < n) p[i] = 0;
}

__global__ void count_kernel(const int* __restrict__ ei, int* __restrict__ cnt) {
  int e = blockIdx.x * 256 + threadIdx.x;
  if (e < E_N) atomicAdd(&cnt[ei[E_N + e]], 1);
}

// per-chunk local scan + atomic ticket for block base (CSR rows may be laid out in any
// order across chunks; agg uses cnt[d] for length, never rowstart[d+1]).
// Also computes dinv and 1/||topk_w||.
__global__ __launch_bounds__(1024) void scan_kernel(const int* __restrict__ cnt,
                                                    int* __restrict__ rowstart,
                                                    float* __restrict__ dinv,
                                                    int* __restrict__ gctr,
                                                    const float* __restrict__ topk_w,
                                                    float* __restrict__ scal) {
  __shared__ int buf[1024];
  __shared__ int base;
  int tid = threadIdx.x;
  int i = blockIdx.x * 1024 + tid;
  int v = (i < N_G) ? cnt[i] : 0;
  if (i < N_G) dinv[i] = 1.0f / sqrtf((float)(v + 1));  // +1 = self loop
  buf[tid] = v;
  __syncthreads();
  for (int s = 1; s < 1024; s <<= 1) {
    int t = (tid >= s) ? buf[tid - s] : 0;
    __syncthreads();
    buf[tid] += t;
    __syncthreads();
  }
  if (tid == 1023) base = atomicAdd(gctr, buf[1023]);
  __syncthreads();
  if (i < N_G) rowstart[i] = base + buf[tid] - v;
  if (blockIdx.x == 0) {
    __shared__ float fbuf[512];
    if (tid < 512) {
      float w = (tid < 384) ? topk_w[tid] : 0.f;
      fbuf[tid] = w * w;
    }
    __syncthreads();
    for (int s = 256; s > 0; s >>= 1) {
      if (tid < s) fbuf[tid] += fbuf[tid + s];
      __syncthreads();
    }
    if (tid == 0) scal[0] = 1.0f / sqrtf(fbuf[0]);
  }
}

__global__ void fill_kernel(const int* __restrict__ ei, const int* __restrict__ rowstart,
                            const float* __restrict__ dinv, int* __restrict__ fillc,
                            int2* __restrict__ csr) {
  int e = blockIdx.x * 256 + threadIdx.x;
  if (e < E_N) {
    int s = ei[e], d = ei[E_N + e];
    int pos = rowstart[d] + atomicAdd(&fillc[d], 1);
    csr[pos] = make_int2(s, __float_as_int(dinv[s]));
  }
}

// ---------------- dense matmul: out[M][128] = A[M][CIN] @ W[CIN][128] ----------------
// BM=64, BN=128(full), BK=32; 256 threads, 8x4 fragment/thread. Both tiles in LDS so
// the kk-loop has zero global access. LDS 21.5 KB -> 7 blocks/CU -> ~28 waves/CU.
template<int CIN>
__global__ __launch_bounds__(256, 6) void mm_kernel(const float* __restrict__ A,
                                                    const float* __restrict__ W,
                                                    float* __restrict__ out, int M) {
  __shared__ float Ast[32][36];   // [kk][row], pad 64->? rows 64 wide: [32][36] holds 64? no:
  // Ast is [kk][row] for 64 rows: need [32][64+pad] -> use 68? see note below.
  __shared__ float Bst[32][132];  // [kk][col], contiguous b128 write/read, conflict-free
  __shared__ float Ast2[32][68];  // actual A tile storage (64 rows, pad to 68)
  int tid = threadIdx.x;
  int rb0 = blockIdx.x * 64;
  int c0 = (tid & 31) * 4;
  int r0 = (tid >> 5) * 8;
  float acc[8][4];
#pragma unroll
  for (int i = 0; i < 8; i++)
#pragma unroll
    for (int j = 0; j < 4; j++) acc[i][j] = 0.f;

  for (int k0 = 0; k0 < CIN; k0 += 32) {
    // stage A (64 rows x 32 k), transposed into Ast2[kk][row]; 2 passes of 32 rows
    {
      int koff = (tid & 7) * 4;
      int row = tid >> 3;  // 0..31
#pragma unroll
      for (int p = 0; p < 2; ++p) {
        int r = row + p * 32;
        int grow = rb0 + r;
        float4 v = make_float4(0.f, 0.f, 0.f, 0.f);
        if (grow < M) v = *(const float4*)(A + (size_t)grow * CIN + k0 + koff);
        Ast2[koff + 0][r] = v.x; Ast2[koff + 1][r] = v.y;
        Ast2[koff + 2][r] = v.z; Ast2[koff + 3][r] = v.w;
      }
    }
    // stage B (32 k x 128 cols); contiguous float4 -> conflict-free
    {
      int cc = (tid & 31) * 4;
      int kr = tid >> 5;  // 0..7
#pragma unroll
      for (int p = 0; p < 4; ++p) {
        int k = kr + p * 8;
        *(float4*)&Bst[k][cc] = *(const float4*)(W + (size_t)(k0 + k) * NH + cc);
      }
    }
    __syncthreads();
#pragma unroll 4
    for (int kk = 0; kk < 32; ++kk) {
      float a[8], b[4];
      *(float4*)&a[0] = *(const float4*)&Ast2[kk][r0];
      *(float4*)&a[4] = *(const float4*)&Ast2[kk][r0 + 4];
      *(float4*)&b[0] = *(const float4*)&Bst[kk][c0];
#pragma unroll
      for (int i = 0; i < 8; i++)
#pragma unroll
        for (int j = 0; j < 4; j++)
          acc[i][j] = fmaf(a[i], b[j], acc[i][j]);
    }
    __syncthreads();
  }
#pragma unroll
  for (int i = 0; i < 8; i++) {
    int row = rb0 + r0 + i;
    if (row < M)
      *(float4*)(out + (size_t)row * NH + c0) = make_float4(acc[i][0], acc[i][1], acc[i][2], acc[i][3]);
  }
  (void)Ast[0][0];
}

// ---------------- sparse aggregation + bias + relu (all 128 channels) ----------------
__global__ __launch_bounds__(256) void agg_kernel(const float* __restrict__ hw,
                                                  const int2* __restrict__ csr,
                                                  const int* __restrict__ rowstart,
                                                  const int* __restrict__ cnt,
                                                  const float* __restrict__ dinv,
                                                  const float* __restrict__ bias,
                                                  float* __restrict__ hout) {
  int b = blockIdx.x & 7;
  int chunk = blockIdx.x >> 3;
  int wave = threadIdx.x >> 6, lane = threadIdx.x & 63;
  int d = chunk * 4 + wave;
  if (d >= N_G) return;
  const float2* hwb = (const float2*)(hw + (size_t)b * N_G * NH);
  float dv = dinv[d];
  int e0 = rowstart[d];
  int n = cnt[d];
  float2 vd = hwb[(size_t)d * 64 + lane];
  float a0x = dv * vd.x, a0y = dv * vd.y;
  float a1x = 0.f, a1y = 0.f, a2x = 0.f, a2y = 0.f, a3x = 0.f, a3y = 0.f;
  for (int l0 = 0; l0 < n; l0 += 64) {
    int idx = l0 + lane;
    int2 p = make_int2(0, 0);
    if (idx < n) p = csr[e0 + idx];
    int m = n - l0; if (m > 64) m = 64;
    int l = 0;
    for (; l + 4 <= m; l += 4) {
      int   s0 = __shfl(p.x, l + 0), s1 = __shfl(p.x, l + 1);
      int   s2 = __shfl(p.x, l + 2), s3 = __shfl(p.x, l + 3);
      float w0 = __int_as_float(__shfl(p.y, l + 0));
      float w1 = __int_as_float(__shfl(p.y, l + 1));
      float w2 = __int_as_float(__shfl(p.y, l + 2));
      float w3 = __int_as_float(__shfl(p.y, l + 3));
      float2 v0 = hwb[(size_t)s0 * 64 + lane];
      float2 v1 = hwb[(size_t)s1 * 64 + lane];
      float2 v2 = hwb[(size_t)s2 * 64 + lane];
      float2 v3 = hwb[(size_t)s3 * 64 + lane];
      a0x = fmaf(w0, v0.x, a0x); a0y = fmaf(w0, v0.y, a0y);
      a1x = fmaf(w1, v1.x, a1x); a1y = fmaf(w1, v1.y, a1y);
      a2x = fmaf(w2, v2.x, a2x); a2y = fmaf(w2, v2.y, a2y);
      a3x = fmaf(w3, v3.x, a3x); a3y = fmaf(w3, v3.y, a3y);
    }
    for (; l < m; ++l) {
      int   s = __shfl(p.x, l);
      float w = __int_as_float(__shfl(p.y, l));
      float2 v = hwb[(size_t)s * 64 + lane];
      a0x = fmaf(w, v.x, a0x); a0y = fmaf(w, v.y, a0y);
    }
  }
  float sx = a0x + a1x + a2x + a3x;
  float sy = a0y + a1y + a2y + a3y;
  float2 bb = ((const float2*)bias)[lane];
  float2 r;
  r.x = fmaxf(fmaf(dv, sx, bb.x), 0.f);
  r.y = fmaxf(fmaf(dv, sy, bb.y), 0.f);
  ((float2*)hout)[((size_t)b * N_G + d) * 64 + lane] = r;
}

// ---------------- layer-3 aggregation fused with score/key/fc-dot (h3 never stored) ----
__global__ __launch_bounds__(256) void agg_score_kernel(const float* __restrict__ hw,
                                                        const int2* __restrict__ csr,
                                                        const int* __restrict__ rowstart,
                                                        const int* __restrict__ cnt,
                                                        const float* __restrict__ dinv,
                                                        const float* __restrict__ bias,
                                                        const float* __restrict__ h1,
                                                        const float* __restrict__ h2,
                                                        const float* __restrict__ topk_w,
                                                        const float* __restrict__ fcW,
                                                        const float* __restrict__ scal,
                                                        unsigned long long* __restrict__ keys,
                                                        float* __restrict__ score,
                                                        float* __restrict__ d2a) {
  int b = blockIdx.x & 7;
  int chunk = blockIdx.x >> 3;
  int wave = threadIdx.x >> 6, lane = threadIdx.x & 63;
  int d = chunk * 4 + wave;
  if (d >= N_G) return;
  const float2* hwb = (const float2*)(hw + (size_t)b * N_G * NH);
  float dv = dinv[d];
  int e0 = rowstart[d];
  int n = cnt[d];
  float2 vd = hwb[(size_t)d * 64 + lane];
  float a0x = dv * vd.x, a0y = dv * vd.y;
  float a1x = 0.f, a1y = 0.f, a2x = 0.f, a2y = 0.f, a3x = 0.f, a3y = 0.f;
  for (int l0 = 0; l0 < n; l0 += 64) {
    int idx = l0 + lane;
    int2 p = make_int2(0, 0);
    if (idx < n) p = csr[e0 + idx];
    int m = n - l0; if (m > 64) m = 64;
    int l = 0;
    for (; l + 4 <= m; l += 4) {
      int   s0 = __shfl(p.x, l + 0), s1 = __shfl(p.x, l + 1);
      int   s2 = __shfl(p.x, l + 2), s3 = __shfl(p.x, l + 3);
      float w0 = __int_as_float(__shfl(p.y, l + 0));
      float w1 = __int_as_float(__shfl(p.y, l + 1));
      float w2 = __int_as_float(__shfl(p.y, l + 2));
      float w3 = __int_as_float(__shfl(p.y, l + 3));
      float2 v0 = hwb[(size_t)s0 * 64 + lane];
      float2 v1 = hwb[(size_t)s1 * 64 + lane];
      float2 v2 = hwb[(size_t)s2 * 64 + lane];
      float2 v3 = hwb[(size_t)s3 * 64 + lane];
      a0x = fmaf(w0, v0.x, a0x); a0y = fmaf(w0, v0.y, a0y);
      a1x = fmaf(w1, v1.x, a1x); a1y = fmaf(w1, v1.y, a1y);
      a2x = fmaf(w2, v2.x, a2x); a2y = fmaf(w2, v2.y, a2y);
      a3x = fmaf(w3, v3.x, a3x); a3y = fmaf(w3, v3.y, a3y);
    }
    for (; l < m; ++l) {
      int   s = __shfl(p.x, l);
      float w = __int_as_float(__shfl(p.y, l));
      float2 v = hwb[(size_t)s * 64 + lane];
      a0x = fmaf(w, v.x, a0x); a0y = fmaf(w, v.y, a0y);
    }
  }
  float sx = a0x + a1x + a2x + a3x;
  float sy = a0y + a1y + a2y + a3y;
  float2 bb = ((const float2*)bias)[lane];
  float2 r;
  r.x = fmaxf(fmaf(dv, sx, bb.x), 0.f);
  r.y = fmaxf(fmaf(dv, sy, bb.y), 0.f);
  // fused score: read h1,h2 rows, dot with topk_w and fcW in xc order (f = h*3 + layer)
  size_t rbase = ((size_t)b * N_G + d) * 64 + lane;
  float2 u1 = ((const float2*)h1)[rbase];
  float2 u2 = ((const float2*)h2)[rbase];
  const float2* tw2 = (const float2*)topk_w;
  const float2* fw2 = (const float2*)fcW;
  float2 ta = tw2[lane * 3 + 0], tb = tw2[lane * 3 + 1], tc = tw2[lane * 3 + 2];
  float2 fa = fw2[lane * 3 + 0], fb = fw2[lane * 3 + 1], fc = fw2[lane * 3 + 2];
  float d1 = u1.x * ta.x + u2.x * ta.y + r.x * tb.x
           + u1.y * tb.y + u2.y * tc.x + r.y * tc.y;
  float d2 = u1.x * fa.x + u2.x * fa.y + r.x * fb.x
           + u1.y * fb.y + u2.y * fc.x + r.y * fc.y;
#pragma unroll
  for (int s = 32; s > 0; s >>= 1) {
    d1 += __shfl_down(d1, s);
    d2 += __shfl_down(d2, s);
  }
  if (lane == 0) {
    int gw = b * N_G + d;
    float sc = tanhf(d1 * scal[0]);
    score[gw] = sc;
    d2a[gw] = d2;
    unsigned int u = __float_as_uint(sc);
    unsigned int k32 = (u & 0x80000000u) ? ~u : (u | 0x80000000u);  // monotone float->u32
    keys[gw] = ((unsigned long long)k32 << 32) | (unsigned long long)(0xFFFFFFFFu - (unsigned)d);
  }
}

// ---------------- exact descending rank: VGPR i-keys vs scalar-broadcast j-keys ----------
// grid x = ib(8) * js(32) -> 2048 blocks total = 8 blocks/CU (32 waves/CU, 100% slots).
#define RANK_JS  32
#define RANK_JCH 473  // ceil(15135/32)
__global__ __launch_bounds__(256) void rank_kernel(const unsigned long long* __restrict__ keys,
                                                   int* __restrict__ rank) {
  int b = blockIdx.y;
  int ib = blockIdx.x >> 5;          // 0..7  i-blocks of 2048
  int js = blockIdx.x & (RANK_JS-1); // 0..31 j-splits of RANK_JCH
  const unsigned long long* kb = keys + (size_t)b * N_G;
  int tid = threadIdx.x;
  int i0 = ib * 2048 + tid;
  unsigned long long ki[8];
  int cnt[8];
#pragma unroll
  for (int t = 0; t < 8; t++) {
    int i = i0 + t * 256;
    ki[t] = (i < N_G) ? kb[i] : ~0ull;
    cnt[t] = 0;
  }
  int j0 = js * RANK_JCH;
  int j1 = j0 + RANK_JCH; if (j1 > N_G) j1 = N_G;
  int j = j0;
  for (; j + 8 <= j1; j += 8) {
    unsigned long long k0 = kb[j + 0], k1 = kb[j + 1], k2 = kb[j + 2], k3 = kb[j + 3];
    unsigned long long k4 = kb[j + 4], k5 = kb[j + 5], k6 = kb[j + 6], k7 = kb[j + 7];
#pragma unroll
    for (int t = 0; t < 8; t++) {
      cnt[t] += (k0 > ki[t]); cnt[t] += (k1 > ki[t]);
      cnt[t] += (k2 > ki[t]); cnt[t] += (k3 > ki[t]);
      cnt[t] += (k4 > ki[t]); cnt[t] += (k5 > ki[t]);
      cnt[t] += (k6 > ki[t]); cnt[t] += (k7 > ki[t]);
    }
  }
  for (; j < j1; ++j) {
    unsigned long long kj = kb[j];
#pragma unroll
    for (int t = 0; t < 8; t++) cnt[t] += (kj > ki[t]) ? 1 : 0;
  }
#pragma unroll
  for (int t = 0; t < 8; t++) {
    int i = i0 + t * 256;
    if (i < N_G && cnt[t] > 0) atomicAdd(&rank[b * N_G + i], cnt[t]);
  }
}

__global__ void scat_kernel(const int* __restrict__ rank, const float* __restrict__ score,
                            const float* __restrict__ d2a, const float* __restrict__ fcb,
                            float* __restrict__ z) {
  int b = blockIdx.y;
  int i = blockIdx.x * 256 + threadIdx.x;
  if (i < N_G) {
    int r = rank[b * N_G + i];
    if (r < K_TOP) z[b * K_TOP + r] = fmaf(score[b * N_G + i], d2a[b * N_G + i], fcb[0]);
  }
}

// ---------------- lin1: hpre[b][c] += sum_r z[b][r]*W[r][c] (r-split + atomics) ----------------
__global__ __launch_bounds__(256) void lin1_kernel(const float* __restrict__ z,
                                                   const float* __restrict__ W,
                                                   float* __restrict__ hpre) {
  __shared__ float zb[237];
  int b = blockIdx.y, rs = blockIdx.x;
  int r0 = rs * 237;
  int rn = K_TOP - r0; if (rn > 237) rn = 237;
  for (int q = threadIdx.x; q < rn; q += 256) zb[q] = z[b * K_TOP + r0 + q];
  __syncthreads();
  int c = threadIdx.x;
  float a0 = 0.f, a1 = 0.f;
  for (int r = 0; r < rn; ++r) {
    float zz = zb[r];
    const float* wr = W + (size_t)(r0 + r) * 512;
    a0 = fmaf(zz, wr[c], a0);
    a1 = fmaf(zz, wr[c + 256], a1);
  }
  atomicAdd(&hpre[b * 512 + c], a0);
  atomicAdd(&hpre[b * 512 + c + 256], a1);
}

// ---------------- lin2 + log_softmax ----------------
__global__ __launch_bounds__(128) void lin2_kernel(const float* __restrict__ hpre,
                                                   const float* __restrict__ l1b,
                                                   const float* __restrict__ W2,
                                                   const float* __restrict__ l2b,
                                                   float* __restrict__ out) {
  int b = blockIdx.x, tid = threadIdx.x;
  float a0 = 0.f, a1 = 0.f;
  for (int j = tid; j < 512; j += 128) {
    float t = fmaxf(hpre[b * 512 + j] + l1b[j], 0.f);
    a0 = fmaf(t, W2[j * 2 + 0], a0);
    a1 = fmaf(t, W2[j * 2 + 1], a1);
  }
#pragma unroll
  for (int s = 32; s > 0; s >>= 1) {
    a0 += __shfl_down(a0, s);
    a1 += __shfl_down(a1, s);
  }
  __shared__ float red[2][2];
  if ((tid & 63) == 0) { red[tid >> 6][0] = a0; red[tid >> 6][1] = a1; }
  __syncthreads();
  if (tid == 0) {
    float l0 = red[0][0] + red[1][0] + l2b[0];
    float l1 = red[0][1] + red[1][1] + l2b[1];
    float m = fmaxf(l0, l1);
    float lse = m + logf(expf(l0 - m) + expf(l1 - m));
    out[b * 2 + 0] = l0 - lse;
    out[b * 2 + 1] = l1 - lse;
  }
}

extern "C" void kernel_launch(void* const* d_in, const int* in_sizes, int n_in,
                              void* d_out, int out_size, void* d_ws, size_t ws_size,
                              hipStream_t stream) {
  const float* x   = (const float*)d_in[0];
  const int*   ei  = (const int*)d_in[2];
  const float* W1  = (const float*)d_in[3];
  const float* b1  = (const float*)d_in[4];
  const float* W2  = (const float*)d_in[5];
  const float* b2  = (const float*)d_in[6];
  const float* W3  = (const float*)d_in[7];
  const float* b3  = (const float*)d_in[8];
  const float* tkw = (const float*)d_in[9];
  const float* fcW = (const float*)d_in[10];
  const float* fcb = (const float*)d_in[11];
  const float* l1W = (const float*)d_in[12];
  const float* l1b = (const float*)d_in[13];
  const float* l2W = (const float*)d_in[14];
  const float* l2b = (const float*)d_in[15];
  float* out = (float*)d_out;

  char* ws = (char*)d_ws;
  size_t off = 0;
  auto alloc = [&](size_t bytes) {
    char* p = ws + off;
    off += (bytes + 255) & ~(size_t)255;
    return p;
  };
  // zero-init region (contiguous): cnt, fillc, gctr, rank, hpre
  int*   cnt   = (int*)alloc(15136 * 4);
  int*   fillc = (int*)alloc(15136 * 4);
  int*   gctr  = (int*)alloc(256);
  int*   rank  = (int*)alloc(121088 * 4);
  float* hpre  = (float*)alloc(4096 * 4);
  int*   rowstart = (int*)alloc(15136 * 4);
  float* dinv  = (float*)alloc(15136 * 4);
  float* scal  = (float*)alloc(64);
  float* z     = (float*)alloc((size_t)BSZ * K_TOP * 4);
  float* score = (float*)alloc(121088 * 4);
  float* d2a   = (float*)alloc(121088 * 4);
  unsigned long long* keys = (unsigned long long*)alloc(121088 * 8);
  int2*  csr   = (int2*)alloc((size_t)E_N * 8);
  float* hw = (float*)alloc((size_t)BSZ * N_G * NH * 4);
  float* h1 = (float*)alloc((size_t)BSZ * N_G * NH * 4);
  float* h2 = (float*)alloc((size_t)BSZ * N_G * NH * 4);
  (void)ws_size; (void)in_sizes; (void)n_in; (void)out_size;

  int zero_n = (int)(((char*)rowstart - (char*)cnt) / 4);
  zero_kernel<<<(zero_n + 1023) / 1024, 1024, 0, stream>>>(cnt, zero_n);
  count_kernel<<<(E_N + 255) / 256, 256, 0, stream>>>(ei, cnt);
  scan_kernel<<<(N_G + 1023) / 1024, 1024, 0, stream>>>(cnt, rowstart, dinv, gctr, tkw, scal);
  fill_kernel<<<(E_N + 255) / 256, 256, 0, stream>>>(ei, rowstart, dinv, fillc, csr);

  int M = BSZ * N_G;
  dim3 mmg((M + 63) / 64);
  int aggblocks = 8 * ((N_G + 3) / 4);

  mm_kernel<64><<<mmg, 256, 0, stream>>>(x, W1, hw, M);
  agg_kernel<<<aggblocks, 256, 0, stream>>>(hw, csr, rowstart, cnt, dinv, b1, h1);
  mm_kernel<128><<<mmg, 256, 0, stream>>>(h1, W2, hw, M);
  agg_kernel<<<aggblocks, 256, 0, stream>>>(hw, csr, rowstart, cnt, dinv, b2, h2);
  mm_kernel<128><<<mmg, 256, 0, stream>>>(h2, W3, hw, M);
  agg_score_kernel<<<aggblocks, 256, 0, stream>>>(hw, csr, rowstart, cnt, dinv, b3,
                                                  h1, h2, tkw, fcW, scal, keys, score, d2a);

  dim3 rg(8 * RANK_JS, BSZ);
  rank_kernel<<<rg, 256, 0, stream>>>(keys, rank);
  dim3 scg((N_G + 255) / 256, BSZ);
  scat_kernel<<<scg, 256, 0, stream>>>(rank, score, d2a, fcb, z);
  dim3 l1g(32, BSZ);
  lin1_kernel<<<l1g, 256, 0, stream>>>(z, l1W, hpre);
  lin2_kernel<<<BSZ, 128, 0, stream>>>(hpre, l1b, l2W, l2b, out);
}